// Round 1
// baseline (2565.949 us; speedup 1.0000x reference)
//
#include <hip/hip_runtime.h>
#include <hip/hip_bf16.h>

typedef __attribute__((ext_vector_type(4))) float f32x4;
typedef __attribute__((ext_vector_type(8))) short bf16x8;

#define NL 6
#define BS 2048          // B*S = 4*512
#define BHS 16384        // B*H*S
#define RW 1025          // rel width

static __device__ __forceinline__ unsigned short f2bf(float f) {
    __hip_bfloat16 h = __float2bfloat16(f);
    return *reinterpret_cast<unsigned short*>(&h);
}
static __device__ __forceinline__ float bf2f(unsigned short u) {
    union { unsigned int u32; float f; } c; c.u32 = ((unsigned int)u) << 16; return c.f;
}
static __device__ __forceinline__ float gelu_exact(float v) {
    return 0.5f * v * (1.0f + erff(v * 0.70710678118654752f));
}

// Generic batched GEMM: C = alpha*op(A)@op(B) (+C) (+bias) (gelu)
// A: [M,K] lda (f32 or bf16). B: NN -> B[k*ldb+n], NT -> B[n*ldb+k] (f32).
// batch offset for X = (z%modX)*sX1 + (z/modX)*sX2 (elements).
template<bool TB, bool ABF, bool CBF, bool ACC, bool BIAS, bool GACT>
__global__ __launch_bounds__(256)
void gemm_k(const void* __restrict__ Ap, const float* __restrict__ Bp,
            void* __restrict__ Cp, const float* __restrict__ bias,
            int M, int N, int K, int lda, int ldb, int ldc, float alpha,
            int modA, long sA1, long sA2,
            int modB, long sB1, long sB2,
            int modC, long sC1, long sC2,
            long biasStride)
{
    __shared__ __attribute__((aligned(16))) unsigned short Al[64][40];
    __shared__ __attribute__((aligned(16))) unsigned short Bl[64][40];

    const int z = blockIdx.z;
    const long offA = (long)(z % modA) * sA1 + (long)(z / modA) * sA2;
    const long offB = (long)(z % modB) * sB1 + (long)(z / modB) * sB2;
    const long offC = (long)(z % modC) * sC1 + (long)(z / modC) * sC2;
    const float* Af = (const float*)Ap + offA;
    const unsigned short* Ah = (const unsigned short*)Ap + offA;
    const float* Bf = Bp + offB;
    float* Cf = (float*)Cp + offC;
    unsigned short* Ch = (unsigned short*)Cp + offC;
    const float* bi = BIAS ? (bias + (long)z * biasStride) : nullptr;

    const int bm0 = blockIdx.x * 64, bn0 = blockIdx.y * 64;
    const int t = threadIdx.x;
    const int lane = t & 63, w = t >> 6;
    const int wm = (w >> 1) * 32, wn = (w & 1) * 32;

    f32x4 acc[2][2];
    #pragma unroll
    for (int a = 0; a < 2; a++)
        #pragma unroll
        for (int b = 0; b < 2; b++) acc[a][b] = (f32x4){0.f, 0.f, 0.f, 0.f};

    const int nk = (K + 31) >> 5;
    for (int kt = 0; kt < nk; ++kt) {
        const int k0 = kt << 5;
        __syncthreads();
        // ---- stage A tile [64][32] ----
        #pragma unroll
        for (int it = 0; it < 2; ++it) {
            int idx = t + it * 256;
            int r = idx >> 3, c4 = (idx & 7) << 2;
            int gr = bm0 + r, gk = k0 + c4;
            unsigned short u0 = 0, u1 = 0, u2 = 0, u3 = 0;
            if (gr < M) {
                if (!ABF) {
                    if (gk + 4 <= K) {
                        const float4 v = *(const float4*)(Af + (long)gr * lda + gk);
                        u0 = f2bf(v.x); u1 = f2bf(v.y); u2 = f2bf(v.z); u3 = f2bf(v.w);
                    } else {
                        const float* p = Af + (long)gr * lda;
                        if (gk + 0 < K) u0 = f2bf(p[gk + 0]);
                        if (gk + 1 < K) u1 = f2bf(p[gk + 1]);
                        if (gk + 2 < K) u2 = f2bf(p[gk + 2]);
                        if (gk + 3 < K) u3 = f2bf(p[gk + 3]);
                    }
                } else {
                    const unsigned short* p = Ah + (long)gr * lda;
                    if (gk + 0 < K) u0 = p[gk + 0];
                    if (gk + 1 < K) u1 = p[gk + 1];
                    if (gk + 2 < K) u2 = p[gk + 2];
                    if (gk + 3 < K) u3 = p[gk + 3];
                }
            }
            Al[r][c4 + 0] = u0; Al[r][c4 + 1] = u1; Al[r][c4 + 2] = u2; Al[r][c4 + 3] = u3;
        }
        // ---- stage B tile -> Bl[n][k] ----
        #pragma unroll
        for (int it = 0; it < 2; ++it) {
            int idx = t + it * 256;
            if (TB) {
                int r = idx >> 3, c4 = (idx & 7) << 2;
                int gn = bn0 + r, gk = k0 + c4;
                unsigned short u0 = 0, u1 = 0, u2 = 0, u3 = 0;
                if (gn < N) {
                    if (gk + 4 <= K) {
                        const float4 v = *(const float4*)(Bf + (long)gn * ldb + gk);
                        u0 = f2bf(v.x); u1 = f2bf(v.y); u2 = f2bf(v.z); u3 = f2bf(v.w);
                    } else {
                        const float* p = Bf + (long)gn * ldb;
                        if (gk + 0 < K) u0 = f2bf(p[gk + 0]);
                        if (gk + 1 < K) u1 = f2bf(p[gk + 1]);
                        if (gk + 2 < K) u2 = f2bf(p[gk + 2]);
                        if (gk + 3 < K) u3 = f2bf(p[gk + 3]);
                    }
                }
                Bl[r][c4 + 0] = u0; Bl[r][c4 + 1] = u1; Bl[r][c4 + 2] = u2; Bl[r][c4 + 3] = u3;
            } else {
                int k = idx >> 4, n4 = (idx & 15) << 2;
                int gk = k0 + k, gn0 = bn0 + n4;
                float x0 = 0.f, x1 = 0.f, x2 = 0.f, x3 = 0.f;
                if (gk < K) {
                    if (gn0 + 4 <= N) {
                        const float4 v = *(const float4*)(Bf + (long)gk * ldb + gn0);
                        x0 = v.x; x1 = v.y; x2 = v.z; x3 = v.w;
                    } else {
                        const float* p = Bf + (long)gk * ldb;
                        if (gn0 + 0 < N) x0 = p[gn0 + 0];
                        if (gn0 + 1 < N) x1 = p[gn0 + 1];
                        if (gn0 + 2 < N) x2 = p[gn0 + 2];
                        if (gn0 + 3 < N) x3 = p[gn0 + 3];
                    }
                }
                Bl[n4 + 0][k] = f2bf(x0); Bl[n4 + 1][k] = f2bf(x1);
                Bl[n4 + 2][k] = f2bf(x2); Bl[n4 + 3][k] = f2bf(x3);
            }
        }
        __syncthreads();
        // ---- compute: 2x2 MFMA 16x16x32 ----
        const int fr = lane & 15, k8 = (lane >> 4) << 3;
        bf16x8 a0 = *(const bf16x8*)&Al[wm + fr][k8];
        bf16x8 a1 = *(const bf16x8*)&Al[wm + 16 + fr][k8];
        bf16x8 b0 = *(const bf16x8*)&Bl[wn + fr][k8];
        bf16x8 b1 = *(const bf16x8*)&Bl[wn + 16 + fr][k8];
        acc[0][0] = __builtin_amdgcn_mfma_f32_16x16x32_bf16(a0, b0, acc[0][0], 0, 0, 0);
        acc[0][1] = __builtin_amdgcn_mfma_f32_16x16x32_bf16(a0, b1, acc[0][1], 0, 0, 0);
        acc[1][0] = __builtin_amdgcn_mfma_f32_16x16x32_bf16(a1, b0, acc[1][0], 0, 0, 0);
        acc[1][1] = __builtin_amdgcn_mfma_f32_16x16x32_bf16(a1, b1, acc[1][1], 0, 0, 0);
    }
    // ---- epilogue: C/D layout col=lane&15, row=(lane>>4)*4+j ----
    const int fr = lane & 15, q4 = (lane >> 4) << 2;
    #pragma unroll
    for (int mi = 0; mi < 2; mi++)
        #pragma unroll
        for (int ni = 0; ni < 2; ni++)
            #pragma unroll
            for (int j = 0; j < 4; j++) {
                int gr = bm0 + wm + mi * 16 + q4 + j;
                int gc = bn0 + wn + ni * 16 + fr;
                if (gr < M && gc < N) {
                    float v = acc[mi][ni][j] * alpha;
                    if (ACC) v += Cf[(long)gr * ldc + gc];
                    if (BIAS) v += bi[gc];
                    if (GACT) v = gelu_exact(v);
                    if (CBF) Ch[(long)gr * ldc + gc] = f2bf(v);
                    else     Cf[(long)gr * ldc + gc] = v;
                }
            }
}

// softmax over scores rows with rel-k bias gather (row-contiguous in j)
__global__ __launch_bounds__(256)
void softmax_rel_k(float* __restrict__ sc, const unsigned short* __restrict__ qrel)
{
    int wv = threadIdx.x >> 6, lane = threadIdx.x & 63;
    long row = (long)blockIdx.x * 4 + wv;        // (b*8+h)*512 + i
    int b = (int)(row >> 12);
    int h = (int)((row >> 9) & 7);
    int i = (int)(row & 511);
    float* p = sc + row * 512;
    const unsigned short* qr = qrel + ((long)((b * 512 + i) * 8 + h)) * RW + (512 - i);
    float v[8]; float mx = -1e30f;
    #pragma unroll
    for (int jj = 0; jj < 8; jj++) {
        int j = jj * 64 + lane;
        float x = p[j] + bf2f(qr[j]);
        v[jj] = x; mx = fmaxf(mx, x);
    }
    #pragma unroll
    for (int off = 32; off; off >>= 1) mx = fmaxf(mx, __shfl_xor(mx, off));
    float s = 0.f;
    #pragma unroll
    for (int jj = 0; jj < 8; jj++) { v[jj] = expf(v[jj] - mx); s += v[jj]; }
    #pragma unroll
    for (int off = 32; off; off >>= 1) s += __shfl_xor(s, off);
    float inv = 1.f / s;
    #pragma unroll
    for (int jj = 0; jj < 8; jj++) p[jj * 64 + lane] = v[jj] * inv;
}

// ar[m][r] = a[b,h,i, i+r-512] (0 outside), m=(b*512+i)*8+h, bf16
__global__ __launch_bounds__(256)
void ar_build_k(const float* __restrict__ a, unsigned short* __restrict__ ar)
{
    int m = blockIdx.x;
    int b = m >> 12, i = (m >> 3) & 511, h = m & 7;
    const float* arow = a + (((long)(b * 8 + h)) * 512 + i) * 512;
    unsigned short* dst = ar + (long)m * RW;
    for (int r = threadIdx.x; r < RW; r += 256) {
        int j = i + r - 512;
        float val = (j >= 0 && j < 512) ? arow[j] : 0.f;
        dst[r] = f2bf(val);
    }
}

// out = LN(a + b) * g + be, rows of 512, one wave per row
__global__ __launch_bounds__(256)
void ln_add_k(const float* __restrict__ a, const float* __restrict__ b2,
              const float* __restrict__ g, const float* __restrict__ be,
              float* __restrict__ o)
{
    int wv = threadIdx.x >> 6, lane = threadIdx.x & 63;
    long row = (long)blockIdx.x * 4 + wv;
    const float* pa = a + row * 512;
    const float* pb = b2 + row * 512;
    float v[8]; float s = 0.f;
    #pragma unroll
    for (int jj = 0; jj < 8; jj++) { int j = jj * 64 + lane; float x = pa[j] + pb[j]; v[jj] = x; s += x; }
    #pragma unroll
    for (int off = 32; off; off >>= 1) s += __shfl_xor(s, off);
    float mean = s * (1.f / 512.f);
    float vs = 0.f;
    #pragma unroll
    for (int jj = 0; jj < 8; jj++) { float d = v[jj] - mean; vs += d * d; }
    #pragma unroll
    for (int off = 32; off; off >>= 1) vs += __shfl_xor(vs, off);
    float inv = rsqrtf(vs * (1.f / 512.f) + 1e-5f);
    float* po = o + row * 512;
    #pragma unroll
    for (int jj = 0; jj < 8; jj++) { int j = jj * 64 + lane; po[j] = (v[jj] - mean) * inv * g[j] + be[j]; }
}

// x = w0*trend + w4*resid + w1*s0 + w2*s1 + w3*s2, w=softmax(comb)
__global__ __launch_bounds__(256)
void combine_k(const float* __restrict__ trend, const float* __restrict__ resid,
               const float* __restrict__ seas, const float* __restrict__ comb,
               float* __restrict__ xo, int n)
{
    float c[5]; float m = -1e30f;
    #pragma unroll
    for (int k = 0; k < 5; k++) { c[k] = comb[k]; m = fmaxf(m, c[k]); }
    float s = 0.f;
    #pragma unroll
    for (int k = 0; k < 5; k++) { c[k] = expf(c[k] - m); s += c[k]; }
    float inv = 1.f / s;
    for (long idx = (long)blockIdx.x * blockDim.x + threadIdx.x; idx < n;
         idx += (long)gridDim.x * blockDim.x) {
        xo[idx] = inv * (c[0] * trend[idx] + c[4] * resid[idx] + c[1] * seas[idx]
                         + c[2] * seas[idx + 1048576] + c[3] * seas[idx + 2097152]);
    }
}

#define GEMM(TB,ABF,CBF,ACC,BIAS,GACT, A,B,C,bias_, M,N,K, lda,ldb,ldc, alpha, mA,a1,a2, mB,b1,b2, mC,c1,c2, bstr, Z) \
    gemm_k<TB,ABF,CBF,ACC,BIAS,GACT><<<dim3(((M)+63)/64, ((N)+63)/64, (Z)), dim3(256), 0, stream>>>( \
        (A),(B),(C),(bias_),(M),(N),(K),(lda),(ldb),(ldc),(alpha), \
        (mA),(long)(a1),(long)(a2),(mB),(long)(b1),(long)(b2),(mC),(long)(c1),(long)(c2),(long)(bstr))

extern "C" void kernel_launch(void* const* d_in, const int* in_sizes, int n_in,
                              void* d_out, int out_size, void* d_ws, size_t ws_size,
                              hipStream_t stream)
{
    (void)in_sizes; (void)n_in; (void)out_size; (void)ws_size;
    const float* x    = (const float*)d_in[0];
    const float* t1w  = (const float*)d_in[1];
    const float* t1b  = (const float*)d_in[2];
    const float* t2w  = (const float*)d_in[3];
    const float* t2b  = (const float*)d_in[4];
    const float* s1w  = (const float*)d_in[5];
    const float* s1b  = (const float*)d_in[6];
    const float* s2w  = (const float*)d_in[7];
    const float* s2b  = (const float*)d_in[8];
    const float* r1w  = (const float*)d_in[9];
    const float* r1b  = (const float*)d_in[10];
    const float* r2w  = (const float*)d_in[11];
    const float* r2b  = (const float*)d_in[12];
    const float* comb = (const float*)d_in[13];
    const float* wq   = (const float*)d_in[14];
    const float* wk   = (const float*)d_in[15];
    const float* wvv  = (const float*)d_in[16];
    const float* wow  = (const float*)d_in[17];
    const float* wob  = (const float*)d_in[18];
    const float* relk = (const float*)d_in[19];
    const float* relv = (const float*)d_in[20];
    const float* lag  = (const float*)d_in[21];
    const float* labi = (const float*)d_in[22];
    const float* f1w  = (const float*)d_in[23];
    const float* f1b  = (const float*)d_in[24];
    const float* f2w  = (const float*)d_in[25];
    const float* f2b  = (const float*)d_in[26];
    const float* n1g  = (const float*)d_in[27];
    const float* n1b  = (const float*)d_in[28];
    const float* n2g  = (const float*)d_in[29];
    const float* n2b  = (const float*)d_in[30];

    char* ws = (char*)d_ws;
    float* X    = (float*)(ws);                    // 4MB  [2048,512]
    float* Qb   = (float*)(ws + (4l  << 20));      // 4MB
    float* Kb   = (float*)(ws + (8l  << 20));      // 4MB
    float* Vb   = (float*)(ws + (12l << 20));      // 4MB
    float* CTX  = (float*)(ws + (16l << 20));      // 4MB
    float* T1   = (float*)(ws + (20l << 20));      // 4MB
    float* T2   = (float*)(ws + (24l << 20));      // 4MB
    float* T3   = (float*)(ws + (28l << 20));      // 4MB
    float* FFb  = (float*)(ws + (32l << 20));      // 16MB [2048,2048] / h[3,2048,256]
    float* SEAS = (float*)(ws + (48l << 20));      // 12MB [3,2048,512]
    float* SC   = (float*)(ws + (64l << 20));      // 33.6MB [4,8,512,512]
    unsigned short* AR = (unsigned short*)(ws + (100l << 20)); // 33.6MB bf16 [16384,1025]

    // ---------------- Seasonal decomposition ----------------
    GEMM(false,false,false,false,true,true,  x,  t1w, T3,  t1b, BS,512,512, 512,512,512, 1.f, 1,0,0, 1,0,0, 1,0,0, 0, 1);
    GEMM(false,false,false,false,true,false, T3, t2w, T1,  t2b, BS,512,512, 512,512,512, 1.f, 1,0,0, 1,0,0, 1,0,0, 0, 1);
    GEMM(false,false,false,false,true,true,  x,  r1w, T3,  r1b, BS,256,512, 512,256,256, 1.f, 1,0,0, 1,0,0, 1,0,0, 0, 1);
    GEMM(false,false,false,false,true,false, T3, r2w, T2,  r2b, BS,512,256, 256,512,512, 1.f, 1,0,0, 1,0,0, 1,0,0, 0, 1);
    GEMM(false,false,false,false,true,true,  x,  s1w, FFb, s1b, BS,256,512, 512,256,256, 1.f, 3,0,0, 3,131072,0, 3,524288,0, 256, 3);
    GEMM(false,false,false,false,true,false, FFb,s2w, SEAS,s2b, BS,512,256, 256,512,512, 1.f, 3,524288,0, 3,131072,0, 3,1048576,0, 512, 3);
    combine_k<<<dim3(2048), dim3(256), 0, stream>>>(T1, T2, SEAS, comb, X, 2048 * 512);

    // ---------------- Transformer layers ----------------
    for (int l = 0; l < NL; ++l) {
        const float* wq_l = wq  + (long)l * 512 * 512;
        const float* wk_l = wk  + (long)l * 512 * 512;
        const float* wv_l = wvv + (long)l * 512 * 512;
        const float* wo_l = wow + (long)l * 512 * 512;
        const float* wob_l = wob + (long)l * 512;
        const float* rk_l = relk + (long)l * RW * 64;
        const float* rv_l = relv + (long)l * RW * 64;
        const float* f1w_l = f1w + (long)l * 512 * 2048;
        const float* f1b_l = f1b + (long)l * 2048;
        const float* f2w_l = f2w + (long)l * 2048 * 512;
        const float* f2b_l = f2b + (long)l * 512;

        // QKV projections
        GEMM(false,false,false,false,false,false, X, wq_l, Qb, nullptr, BS,512,512, 512,512,512, 1.f, 1,0,0, 1,0,0, 1,0,0, 0, 1);
        GEMM(false,false,false,false,false,false, X, wk_l, Kb, nullptr, BS,512,512, 512,512,512, 1.f, 1,0,0, 1,0,0, 1,0,0, 0, 1);
        GEMM(false,false,false,false,false,false, X, wv_l, Vb, nullptr, BS,512,512, 512,512,512, 1.f, 1,0,0, 1,0,0, 1,0,0, 0, 1);

        // scores = 0.125 * Q @ K^T  (batched over 32 (b,h))
        GEMM(true,false,false,false,false,false, Qb, Kb, SC, nullptr, 512,512,64, 512,512,512, 0.125f,
             8,64,262144, 8,64,262144, 32,262144,0, 0, 32);
        // qrel[m,r] = Q_m . rel_k_r  -> bf16 [16384,1025]
        GEMM(true,false,true,false,false,false, Qb, rk_l, AR, nullptr, BHS,RW,64, 64,64,RW, 1.f,
             1,0,0, 1,0,0, 1,0,0, 0, 1);
        // softmax(scores + gather(qrel))
        softmax_rel_k<<<dim3(4096), dim3(256), 0, stream>>>(SC, AR);
        // ctx = A @ V
        GEMM(false,false,false,false,false,false, SC, Vb, CTX, nullptr, 512,64,512, 512,512,512, 1.f,
             32,262144,0, 8,64,262144, 8,64,262144, 0, 32);
        // ar scatter (bf16), then ctx += ar @ rel_v
        ar_build_k<<<dim3(16384), dim3(256), 0, stream>>>(SC, AR);
        GEMM(false,true,false,true,false,false, AR, rv_l, CTX, nullptr, BHS,64,RW, RW,64,64, 1.f,
             1,0,0, 1,0,0, 1,0,0, 0, 1);
        // out = ctx @ wo + b
        GEMM(false,false,false,false,true,false, CTX, wo_l, T1, wob_l, BS,512,512, 512,512,512, 1.f, 1,0,0, 1,0,0, 1,0,0, 0, 1);
        // attn = LN(out + xc); y1 = LN(xc + attn)
        ln_add_k<<<dim3(512), dim3(256), 0, stream>>>(T1, X, lag + l*512, labi + l*512, T2);
        ln_add_k<<<dim3(512), dim3(256), 0, stream>>>(X, T2, n1g + l*512, n1b + l*512, T3);
        // FF
        GEMM(false,false,false,false,true,true,  T3,  f1w_l, FFb, f1b_l, BS,2048,512, 512,2048,2048, 1.f, 1,0,0, 1,0,0, 1,0,0, 0, 1);
        GEMM(false,false,false,false,true,false, FFb, f2w_l, T1,  f2b_l, BS,512,2048, 2048,512,512, 1.f, 1,0,0, 1,0,0, 1,0,0, 0, 1);
        // y = LN(y1 + ff)
        float* outp = (l == NL - 1) ? (float*)d_out : X;
        ln_add_k<<<dim3(512), dim3(256), 0, stream>>>(T3, T1, n2g + l*512, n2b + l*512, outp);
    }
}

// Round 2
// 1454.125 us; speedup vs baseline: 1.7646x; 1.7646x over previous
//
#include <hip/hip_runtime.h>
#include <hip/hip_bf16.h>

typedef __attribute__((ext_vector_type(4))) float f32x4;
typedef __attribute__((ext_vector_type(8))) short bf16x8;
typedef __attribute__((ext_vector_type(4))) short bf16x4;

#define NL 6

static __device__ __forceinline__ unsigned short f2bf(float f) {
    __hip_bfloat16 h = __float2bfloat16(f);
    return *reinterpret_cast<unsigned short*>(&h);
}
static __device__ __forceinline__ float bf2f(unsigned short u) {
    union { unsigned int u32; float f; } c; c.u32 = ((unsigned int)u) << 16; return c.f;
}
static __device__ __forceinline__ float gelu_exact(float v) {
    return 0.5f * v * (1.0f + erff(v * 0.70710678118654752f));
}
static __device__ __forceinline__ void gload_lds16(const void* g, void* l) {
    __builtin_amdgcn_global_load_lds((const __attribute__((address_space(1))) void*)g,
                                     (__attribute__((address_space(3))) void*)l, 16, 0, 0);
}

// ============================ GEMM ============================
// C[M,N] = alpha * A[M,K] @ B^T[N,K]  (+acc) (+bias) (gelu), A/B bf16.
// M % 128 == 0, K % 32 == 0. N guarded (gc < N). BN in {64,128}.
template<int BN, bool OBF, bool ACC, bool BIAS, bool GACT>
__global__ __launch_bounds__(256)
void gemm2(const unsigned short* __restrict__ A, const unsigned short* __restrict__ B,
           void* __restrict__ C, const float* __restrict__ accp, const float* __restrict__ bias,
           int M, int N, int K, int lda, int ldb, int ldc, float alpha,
           int modA, long sA1, long sA2, int modB, long sB1, long sB2,
           int modC, long sC1, long sC2, int biasStride)
{
    constexpr int NI = (BN == 128) ? 4 : 2;
    constexpr int NCH = 8 + BN / 16;           // 1KB staging chunks
    __shared__ __attribute__((aligned(16))) unsigned short Ls[4096 + BN * 32];

    const int z = blockIdx.z;
    const unsigned short* Ab = A + (long)(z % modA) * sA1 + (long)(z / modA) * sA2;
    const unsigned short* Bb = B + (long)(z % modB) * sB1 + (long)(z / modB) * sB2;
    const long offC = (long)(z % modC) * sC1 + (long)(z / modC) * sC2;

    const int bm0 = blockIdx.x * 128, bn0 = blockIdx.y * BN;
    const int t = threadIdx.x, lane = t & 63, w = t >> 6;
    const int wm = (w >> 1) * 64;
    const int wn = (BN == 128) ? (w & 1) * 64 : (w & 1) * 32;

    f32x4 acc[4][NI];
    #pragma unroll
    for (int a = 0; a < 4; a++)
        #pragma unroll
        for (int b = 0; b < NI; b++) acc[a][b] = (f32x4){0.f, 0.f, 0.f, 0.f};

    const int crow = lane >> 2;        // row within 16-row chunk
    const int cs = lane & 3;           // lds k-slot
    const int fr = lane & 15, kq = lane >> 4;
    const int nk = K >> 5;

    for (int kt = 0; kt < nk; ++kt) {
        const int k0 = kt << 5;
        // ---- stage tile: global_load_lds, source XOR-swizzled ----
        #pragma unroll
        for (int c0 = 0; c0 < NCH; c0 += 4) {
            int c = c0 + w;
            if (c < NCH) {
                const unsigned short* gp;
                if (c < 8) {
                    int rit = c * 16 + crow;
                    int ks = cs ^ (rit & 3);
                    gp = Ab + (long)(bm0 + rit) * lda + k0 + ks * 8;
                } else {
                    int rit = (c - 8) * 16 + crow;
                    int ks = cs ^ (rit & 3);
                    gp = Bb + (long)(bn0 + rit) * ldb + k0 + ks * 8;
                }
                gload_lds16(gp, &Ls[c * 512]);
            }
        }
        __syncthreads();   // drains vmcnt before compute
        bf16x8 af[4], bf[NI];
        #pragma unroll
        for (int mi = 0; mi < 4; mi++) {
            int R = wm + mi * 16 + fr;
            af[mi] = *(const bf16x8*)&Ls[R * 32 + ((kq ^ (R & 3)) << 3)];
        }
        #pragma unroll
        for (int ni = 0; ni < NI; ni++) {
            int Rb = wn + ni * 16 + fr;
            bf[ni] = *(const bf16x8*)&Ls[4096 + Rb * 32 + ((kq ^ (Rb & 3)) << 3)];
        }
        #pragma unroll
        for (int mi = 0; mi < 4; mi++)
            #pragma unroll
            for (int ni = 0; ni < NI; ni++)
                acc[mi][ni] = __builtin_amdgcn_mfma_f32_16x16x32_bf16(af[mi], bf[ni], acc[mi][ni], 0, 0, 0);
        __syncthreads();   // protect LDS before next stage
    }

    // ---- epilogue ----
    float* Cf = (float*)C + offC;
    unsigned short* Ch = (unsigned short*)C + offC;
    const float* ap = ACC ? (accp + offC) : nullptr;
    const float* bp = BIAS ? (bias + (long)z * biasStride) : nullptr;
    const int q4 = (lane >> 4) << 2;
    #pragma unroll
    for (int mi = 0; mi < 4; mi++)
        #pragma unroll
        for (int ni = 0; ni < NI; ni++)
            #pragma unroll
            for (int j = 0; j < 4; j++) {
                int gr = bm0 + wm + mi * 16 + q4 + j;
                int gc = bn0 + wn + ni * 16 + fr;
                if (gc < N) {
                    float v = acc[mi][ni][j] * alpha;
                    if (ACC) v += ap[(long)gr * ldc + gc];
                    if (BIAS) v += bp[gc];
                    if (GACT) v = gelu_exact(v);
                    if (OBF) Ch[(long)gr * ldc + gc] = f2bf(v);
                    else     Cf[(long)gr * ldc + gc] = v;
                }
            }
}

// =================== transpose-cast f32 -> bf16^T ===================
// in [Z][R][C] f32 -> out [Z][C][Rp] bf16 (zero-pad rows >= R). C%32==0, Rp%32==0.
__global__ __launch_bounds__(256)
void trcast_k(const float* __restrict__ in, unsigned short* __restrict__ out,
              int R, int C, int Rp, long inStride, long outStride)
{
    __shared__ unsigned short tile[32][33];
    const int z = blockIdx.z;
    const float* ip = in + (long)z * inStride;
    unsigned short* op = out + (long)z * outStride;
    const int c0 = blockIdx.x * 32, r0 = blockIdx.y * 32;
    const int tx = threadIdx.x & 31, ty = threadIdx.x >> 5;
    #pragma unroll
    for (int q = 0; q < 4; q++) {
        int r = r0 + ty + q * 8;
        float v = (r < R) ? ip[(long)r * C + c0 + tx] : 0.f;
        tile[ty + q * 8][tx] = f2bf(v);
    }
    __syncthreads();
    #pragma unroll
    for (int q = 0; q < 4; q++) {
        int c = c0 + ty + q * 8;
        op[(long)c * Rp + r0 + tx] = tile[tx][ty + q * 8];
    }
}

// =================== cast (+row-pad) f32 -> bf16 ===================
__global__ __launch_bounds__(256)
void castpad_k(const float* __restrict__ in, unsigned short* __restrict__ out,
               int R, int C, long inStride, long outStride, long nPerZ)
{
    const int z = blockIdx.z;
    for (long idx = (long)blockIdx.x * 256 + threadIdx.x; idx < nPerZ;
         idx += (long)gridDim.x * 256) {
        int r = (int)(idx / C);
        float v = (r < R) ? in[(long)z * inStride + idx - (long)(r - r) ] : 0.f; // placeholder
        // note: for r < R, in index == idx only when Rp rows beyond R are the pad
        v = (r < R) ? in[(long)z * inStride + idx] : 0.f;
        out[(long)z * outStride + idx] = f2bf(v);
    }
}

// =================== V transpose: [2048][512] bf16 -> [32][64][512] ===================
__global__ __launch_bounds__(256)
void transp_v(const unsigned short* __restrict__ v, unsigned short* __restrict__ vt)
{
    __shared__ unsigned short tile[32][33];
    const int b = blockIdx.z;
    const int j0 = blockIdx.x * 32, c0 = blockIdx.y * 32;
    const int tx = threadIdx.x & 31, ty = threadIdx.x >> 5;
    #pragma unroll
    for (int q = 0; q < 4; q++)
        tile[ty + q * 8][tx] = v[(long)(b * 512 + j0 + ty + q * 8) * 512 + c0 + tx];
    __syncthreads();
    #pragma unroll
    for (int q = 0; q < 4; q++) {
        int c = c0 + ty + q * 8;
        int h = c >> 6, d = c & 63;
        vt[((long)(b * 8 + h) * 64 + d) * 512 + j0 + tx] = tile[tx][ty + q * 8];
    }
}

// =================== softmax with rel-k bias gather ===================
// sc f32 [32*512][512]; qr bf16 [16384][1025]; p bf16 [32*512][512]
__global__ __launch_bounds__(256)
void softmax_rk(const float* __restrict__ sc, const unsigned short* __restrict__ qr,
                unsigned short* __restrict__ p)
{
    const int wv = threadIdx.x >> 6, lane = threadIdx.x & 63;
    const long row = (long)blockIdx.x * 4 + wv;
    const int b = (int)(row >> 12), h = (int)((row >> 9) & 7), i = (int)(row & 511);
    const float* sp = sc + row * 512;
    const unsigned short* qp = qr + ((long)((b * 512 + i) * 8 + h)) * 1025 + (512 - i);
    const int base = lane * 8;
    float v[8];
    float4 a0 = *(const float4*)(sp + base);
    float4 a1 = *(const float4*)(sp + base + 4);
    v[0] = a0.x; v[1] = a0.y; v[2] = a0.z; v[3] = a0.w;
    v[4] = a1.x; v[5] = a1.y; v[6] = a1.z; v[7] = a1.w;
    float mx = -1e30f;
    #pragma unroll
    for (int jj = 0; jj < 8; jj++) { v[jj] += bf2f(qp[base + jj]); mx = fmaxf(mx, v[jj]); }
    #pragma unroll
    for (int off = 32; off; off >>= 1) mx = fmaxf(mx, __shfl_xor(mx, off));
    float s = 0.f;
    #pragma unroll
    for (int jj = 0; jj < 8; jj++) { v[jj] = __expf(v[jj] - mx); s += v[jj]; }
    #pragma unroll
    for (int off = 32; off; off >>= 1) s += __shfl_xor(s, off);
    float inv = 1.f / s;
    bf16x8 o;
    #pragma unroll
    for (int jj = 0; jj < 8; jj++) o[jj] = (short)f2bf(v[jj] * inv);
    *(bf16x8*)(p + row * 512 + base) = o;
}

// =================== AR build: shifted P rows, bf16, [16384][1056] ===================
__global__ __launch_bounds__(256)
void ar_build2(const unsigned short* __restrict__ p, unsigned short* __restrict__ ar)
{
    const int m = blockIdx.x;
    const int b = m >> 12, i = (m >> 3) & 511, h = m & 7;
    const unsigned short* prow = p + ((long)((b * 8 + h) * 512 + i)) * 512;
    unsigned short* dst = ar + (long)m * 1056;
    for (int r = threadIdx.x; r < 1056; r += 256) {
        int j = i + r - 512;
        dst[r] = (j >= 0 && j < 512) ? prow[j] : (unsigned short)0;
    }
}

// =================== LN(a+b): f32 out + bf16 out ===================
__global__ __launch_bounds__(256)
void ln_add2(const float* __restrict__ a, const float* __restrict__ b2,
             const float* __restrict__ g, const float* __restrict__ be,
             float* __restrict__ o, unsigned short* __restrict__ ob)
{
    const int wv = threadIdx.x >> 6, lane = threadIdx.x & 63;
    const long row = (long)blockIdx.x * 4 + wv;
    const int base = lane * 8;
    const float* pa = a + row * 512 + base;
    const float* pb = b2 + row * 512 + base;
    float v[8];
    {
        float4 x0 = *(const float4*)pa, x1 = *(const float4*)(pa + 4);
        float4 y0 = *(const float4*)pb, y1 = *(const float4*)(pb + 4);
        v[0] = x0.x + y0.x; v[1] = x0.y + y0.y; v[2] = x0.z + y0.z; v[3] = x0.w + y0.w;
        v[4] = x1.x + y1.x; v[5] = x1.y + y1.y; v[6] = x1.z + y1.z; v[7] = x1.w + y1.w;
    }
    float s = 0.f;
    #pragma unroll
    for (int jj = 0; jj < 8; jj++) s += v[jj];
    #pragma unroll
    for (int off = 32; off; off >>= 1) s += __shfl_xor(s, off);
    float mean = s * (1.f / 512.f);
    float vs = 0.f;
    #pragma unroll
    for (int jj = 0; jj < 8; jj++) { float d = v[jj] - mean; vs += d * d; }
    #pragma unroll
    for (int off = 32; off; off >>= 1) vs += __shfl_xor(vs, off);
    float inv = rsqrtf(vs * (1.f / 512.f) + 1e-5f);
    float4 g0 = *(const float4*)(g + base), g1 = *(const float4*)(g + base + 4);
    float4 e0 = *(const float4*)(be + base), e1 = *(const float4*)(be + base + 4);
    float gg[8] = {g0.x, g0.y, g0.z, g0.w, g1.x, g1.y, g1.z, g1.w};
    float ee[8] = {e0.x, e0.y, e0.z, e0.w, e1.x, e1.y, e1.z, e1.w};
    float r[8];
    #pragma unroll
    for (int jj = 0; jj < 8; jj++) r[jj] = (v[jj] - mean) * inv * gg[jj] + ee[jj];
    float* po = o + row * 512 + base;
    *(float4*)po = (float4){r[0], r[1], r[2], r[3]};
    *(float4*)(po + 4) = (float4){r[4], r[5], r[6], r[7]};
    bf16x8 ov;
    #pragma unroll
    for (int jj = 0; jj < 8; jj++) ov[jj] = (short)f2bf(r[jj]);
    *(bf16x8*)(ob + row * 512 + base) = ov;
}

// =================== seasonal combine: f32 out + bf16 out ===================
__global__ __launch_bounds__(256)
void combine2(const float* __restrict__ tr, const float* __restrict__ rs,
              const float* __restrict__ se, const float* __restrict__ comb,
              float* __restrict__ xo, unsigned short* __restrict__ xb)
{
    float c[5]; float m = -1e30f;
    #pragma unroll
    for (int k = 0; k < 5; k++) { c[k] = comb[k]; m = fmaxf(m, c[k]); }
    float s = 0.f;
    #pragma unroll
    for (int k = 0; k < 5; k++) { c[k] = __expf(c[k] - m); s += c[k]; }
    float inv = 1.f / s;
    long i4 = ((long)blockIdx.x * 256 + threadIdx.x) * 4;
    float4 t = *(const float4*)(tr + i4);
    float4 r = *(const float4*)(rs + i4);
    float4 s0 = *(const float4*)(se + i4);
    float4 s1 = *(const float4*)(se + 1048576 + i4);
    float4 s2 = *(const float4*)(se + 2097152 + i4);
    float o[4];
    o[0] = inv * (c[0] * t.x + c[4] * r.x + c[1] * s0.x + c[2] * s1.x + c[3] * s2.x);
    o[1] = inv * (c[0] * t.y + c[4] * r.y + c[1] * s0.y + c[2] * s1.y + c[3] * s2.y);
    o[2] = inv * (c[0] * t.z + c[4] * r.z + c[1] * s0.z + c[2] * s1.z + c[3] * s2.z);
    o[3] = inv * (c[0] * t.w + c[4] * r.w + c[1] * s0.w + c[2] * s1.w + c[3] * s2.w);
    *(float4*)(xo + i4) = (float4){o[0], o[1], o[2], o[3]};
    bf16x4 ov = {(short)f2bf(o[0]), (short)f2bf(o[1]), (short)f2bf(o[2]), (short)f2bf(o[3])};
    *(bf16x4*)(xb + i4) = ov;
}

// ============================ host ============================
#define G2(BN,OBF,ACC,BIAS,GACT, A,B,C,accp,bias_, M,N,K, lda,ldb,ldc, alpha, mA,a1,a2, mB,b1,b2, mC,c1,c2, bstr, Z) \
    gemm2<BN,OBF,ACC,BIAS,GACT><<<dim3((M)/128, ((N)+(BN)-1)/(BN), (Z)), dim3(256), 0, stream>>>( \
        (A),(B),(C),(accp),(bias_),(M),(N),(K),(lda),(ldb),(ldc),(alpha), \
        (mA),(long)(a1),(long)(a2),(mB),(long)(b1),(long)(b2),(mC),(long)(c1),(long)(c2),(bstr))

extern "C" void kernel_launch(void* const* d_in, const int* in_sizes, int n_in,
                              void* d_out, int out_size, void* d_ws, size_t ws_size,
                              hipStream_t stream)
{
    (void)in_sizes; (void)n_in; (void)out_size; (void)ws_size;
    const float* x    = (const float*)d_in[0];
    const float* t1w  = (const float*)d_in[1];
    const float* t1b  = (const float*)d_in[2];
    const float* t2w  = (const float*)d_in[3];
    const float* t2b  = (const float*)d_in[4];
    const float* s1w  = (const float*)d_in[5];
    const float* s1b  = (const float*)d_in[6];
    const float* s2w  = (const float*)d_in[7];
    const float* s2b  = (const float*)d_in[8];
    const float* r1w  = (const float*)d_in[9];
    const float* r1b  = (const float*)d_in[10];
    const float* r2w  = (const float*)d_in[11];
    const float* r2b  = (const float*)d_in[12];
    const float* comb = (const float*)d_in[13];
    const float* wq   = (const float*)d_in[14];
    const float* wk   = (const float*)d_in[15];
    const float* wvv  = (const float*)d_in[16];
    const float* wow  = (const float*)d_in[17];
    const float* wob  = (const float*)d_in[18];
    const float* relk = (const float*)d_in[19];
    const float* relv = (const float*)d_in[20];
    const float* lag  = (const float*)d_in[21];
    const float* labi = (const float*)d_in[22];
    const float* f1w  = (const float*)d_in[23];
    const float* f1b  = (const float*)d_in[24];
    const float* f2w  = (const float*)d_in[25];
    const float* f2b  = (const float*)d_in[26];
    const float* n1g  = (const float*)d_in[27];
    const float* n1b  = (const float*)d_in[28];
    const float* n2g  = (const float*)d_in[29];
    const float* n2b  = (const float*)d_in[30];

    char* ws = (char*)d_ws;
    #define OFFK(kb) (ws + (size_t)(kb) * 1024)
    float* X    = (float*)OFFK(0);          // 4MB f32 [2048][512]
    float* T1   = (float*)OFFK(4096);
    float* T2   = (float*)OFFK(8192);
    float* T3   = (float*)OFFK(12288);
    float* CTX  = (float*)OFFK(16384);
    float* SC   = (float*)OFFK(20480);      // 32MB f32 [32][512][512]
    float* SEAS = (float*)OFFK(20480);      // aliases SC (prologue only), 12MB
    unsigned short* Xb   = (unsigned short*)OFFK(53248);  // 2MB bf16 [2048][512]
    unsigned short* Xb0  = (unsigned short*)OFFK(55296);
    unsigned short* Qb   = (unsigned short*)OFFK(57344);
    unsigned short* Kb   = (unsigned short*)OFFK(59392);
    unsigned short* Vb   = (unsigned short*)OFFK(61440);
    unsigned short* VT   = (unsigned short*)OFFK(63488);  // [32][64][512]
    unsigned short* CTXb = (unsigned short*)OFFK(65536);
    unsigned short* T3b  = (unsigned short*)OFFK(67584);
    unsigned short* SHb  = (unsigned short*)OFFK(69632);  // 3MB [3][2048][256]
    unsigned short* FFb  = (unsigned short*)OFFK(72704);  // 8MB [2048][2048]
    unsigned short* SCb  = (unsigned short*)OFFK(80896);  // 16MB [16384][512]
    unsigned short* QRAR = (unsigned short*)OFFK(97280);  // 33MB: QR [16384][1025] then AR [16384][1056]
    unsigned short* wqT  = (unsigned short*)OFFK(131072); // 3MB [6][512][512]
    unsigned short* wkT  = (unsigned short*)OFFK(134144);
    unsigned short* wvT  = (unsigned short*)OFFK(137216);
    unsigned short* woT  = (unsigned short*)OFFK(140288);
    unsigned short* f1wT = (unsigned short*)OFFK(143360); // 12MB [6][2048][512]
    unsigned short* f2wT = (unsigned short*)OFFK(155648); // 12MB [6][512][2048]
    unsigned short* relkp= (unsigned short*)OFFK(167936); // [6][1152][64]
    unsigned short* rvT  = (unsigned short*)OFFK(168800); // [6][64][1056]
    unsigned short* t1wT = (unsigned short*)OFFK(169592); // [512][512]
    unsigned short* t2wT = (unsigned short*)OFFK(170104);
    unsigned short* r1wT = (unsigned short*)OFFK(170616); // [256][512]
    unsigned short* r2wT = (unsigned short*)OFFK(170872); // [512][256]
    unsigned short* s1wT = (unsigned short*)OFFK(171128); // [3][256][512]
    unsigned short* s2wT = (unsigned short*)OFFK(171896); // [3][512][256]

    // ---------------- prep: casts + transposes ----------------
    castpad_k<<<dim3(4096, 1, 1), 256, 0, stream>>>(x, Xb0, 2048, 512, 1048576, 1048576, 1048576);
    trcast_k<<<dim3(16, 16, 1), 256, 0, stream>>>(t1w, t1wT, 512, 512, 512, 262144, 262144);
    trcast_k<<<dim3(16, 16, 1), 256, 0, stream>>>(t2w, t2wT, 512, 512, 512, 262144, 262144);
    trcast_k<<<dim3(8, 16, 1), 256, 0, stream>>>(r1w, r1wT, 512, 256, 512, 131072, 131072);
    trcast_k<<<dim3(16, 8, 1), 256, 0, stream>>>(r2w, r2wT, 256, 512, 256, 131072, 131072);
    trcast_k<<<dim3(8, 16, 3), 256, 0, stream>>>(s1w, s1wT, 512, 256, 512, 131072, 131072);
    trcast_k<<<dim3(16, 8, 3), 256, 0, stream>>>(s2w, s2wT, 256, 512, 256, 131072, 131072);
    trcast_k<<<dim3(16, 16, 6), 256, 0, stream>>>(wq, wqT, 512, 512, 512, 262144, 262144);
    trcast_k<<<dim3(16, 16, 6), 256, 0, stream>>>(wk, wkT, 512, 512, 512, 262144, 262144);
    trcast_k<<<dim3(16, 16, 6), 256, 0, stream>>>(wvv, wvT, 512, 512, 512, 262144, 262144);
    trcast_k<<<dim3(16, 16, 6), 256, 0, stream>>>(wow, woT, 512, 512, 512, 262144, 262144);
    trcast_k<<<dim3(64, 16, 6), 256, 0, stream>>>(f1w, f1wT, 512, 2048, 512, 1048576, 1048576);
    trcast_k<<<dim3(16, 64, 6), 256, 0, stream>>>(f2w, f2wT, 2048, 512, 2048, 1048576, 1048576);
    trcast_k<<<dim3(2, 33, 6), 256, 0, stream>>>(relv, rvT, 1025, 64, 1056, 65600, 67584);
    castpad_k<<<dim3(288, 1, 6), 256, 0, stream>>>(relk, relkp, 1025, 64, 65600, 73728, 73728);

    // ---------------- seasonal decomposition ----------------
    G2(128,true,false,true,true,   Xb0, t1wT, T3b, nullptr, t1b, 2048,512,512, 512,512,512, 1.f, 1,0,0, 1,0,0, 1,0,0, 0, 1);
    G2(128,false,false,true,false, T3b, t2wT, T1,  nullptr, t2b, 2048,512,512, 512,512,512, 1.f, 1,0,0, 1,0,0, 1,0,0, 0, 1);
    G2(128,true,false,true,true,   Xb0, r1wT, SHb, nullptr, r1b, 2048,256,512, 512,512,256, 1.f, 1,0,0, 1,0,0, 1,0,0, 0, 1);
    G2(128,false,false,true,false, SHb, r2wT, T2,  nullptr, r2b, 2048,512,256, 256,256,512, 1.f, 1,0,0, 1,0,0, 1,0,0, 0, 1);
    G2(128,true,false,true,true,   Xb0, s1wT, SHb, nullptr, s1b, 2048,256,512, 512,512,256, 1.f, 1,0,0, 3,131072,0, 3,524288,0, 256, 3);
    G2(128,false,false,true,false, SHb, s2wT, SEAS,nullptr, s2b, 2048,512,256, 256,256,512, 1.f, 3,524288,0, 3,131072,0, 3,1048576,0, 512, 3);
    combine2<<<dim3(1024), 256, 0, stream>>>(T1, T2, SEAS, comb, X, Xb);

    // ---------------- transformer layers ----------------
    for (int l = 0; l < NL; ++l) {
        const unsigned short* wqTl = wqT + (long)l * 262144;
        const unsigned short* wkTl = wkT + (long)l * 262144;
        const unsigned short* wvTl = wvT + (long)l * 262144;
        const unsigned short* woTl = woT + (long)l * 262144;
        const unsigned short* f1Tl = f1wT + (long)l * 1048576;
        const unsigned short* f2Tl = f2wT + (long)l * 1048576;
        const unsigned short* rkl  = relkp + (long)l * 73728;
        const unsigned short* rvl  = rvT + (long)l * 67584;

        G2(128,true,false,false,false, Xb, wqTl, Qb, nullptr, nullptr, 2048,512,512, 512,512,512, 1.f, 1,0,0, 1,0,0, 1,0,0, 0, 1);
        G2(128,true,false,false,false, Xb, wkTl, Kb, nullptr, nullptr, 2048,512,512, 512,512,512, 1.f, 1,0,0, 1,0,0, 1,0,0, 0, 1);
        G2(128,true,false,false,false, Xb, wvTl, Vb, nullptr, nullptr, 2048,512,512, 512,512,512, 1.f, 1,0,0, 1,0,0, 1,0,0, 0, 1);
        transp_v<<<dim3(16, 16, 4), 256, 0, stream>>>(Vb, VT);

        // scores = 0.125 * Q @ K^T (batched over bh)
        G2(128,false,false,false,false, Qb, Kb, SC, nullptr, nullptr, 512,512,64, 512,512,512, 0.125f,
           8,64,262144, 8,64,262144, 1,0,262144, 0, 32);
        // qrel = Q(m-major) @ relk^T -> bf16 [16384][1025]
        G2(128,true,false,false,false, Qb, rkl, QRAR, nullptr, nullptr, 16384,1025,64, 64,64,1025, 1.f,
           1,0,0, 1,0,0, 1,0,0, 0, 1);
        softmax_rk<<<dim3(4096), 256, 0, stream>>>(SC, QRAR, SCb);
        // ctx = P @ V
        G2(64,false,false,false,false, SCb, VT, CTX, nullptr, nullptr, 512,64,512, 512,512,512, 1.f,
           1,0,262144, 1,0,32768, 8,64,262144, 0, 32);
        ar_build2<<<dim3(16384), 256, 0, stream>>>(SCb, QRAR);
        // ctxb = ctx + AR @ rel_v^T  (bf16 out, f32 acc in)
        G2(64,true,true,false,false, QRAR, rvl, CTXb, CTX, nullptr, 16384,64,1056, 1056,1056,64, 1.f,
           1,0,0, 1,0,0, 1,0,0, 0, 1);
        // out = ctxb @ wo + b
        G2(128,false,false,true,false, CTXb, woTl, T1, nullptr, wob + l * 512, 2048,512,512, 512,512,512, 1.f,
           1,0,0, 1,0,0, 1,0,0, 0, 1);
        // attn = LN(out + x); y1 = LN(x + attn)
        ln_add2<<<dim3(512), 256, 0, stream>>>(T1, X, lag + l * 512, labi + l * 512, T2, CTXb);
        ln_add2<<<dim3(512), 256, 0, stream>>>(X, T2, n1g + l * 512, n1b + l * 512, T3, T3b);
        // FF
        G2(128,true,false,true,true,  T3b, f1Tl, FFb, nullptr, f1b + l * 2048, 2048,2048,512, 512,512,2048, 1.f,
           1,0,0, 1,0,0, 1,0,0, 0, 1);
        G2(128,false,false,true,false, FFb, f2Tl, T1, nullptr, f2b + l * 512, 2048,512,2048, 2048,2048,512, 1.f,
           1,0,0, 1,0,0, 1,0,0, 0, 1);
        float* outp = (l == NL - 1) ? (float*)d_out : X;
        ln_add2<<<dim3(512), 256, 0, stream>>>(T3, T1, n2g + l * 512, n2b + l * 512, outp, Xb);
    }
}

// Round 3
// 906.624 us; speedup vs baseline: 2.8302x; 1.6039x over previous
//
#include <hip/hip_runtime.h>
#include <hip/hip_bf16.h>

typedef __attribute__((ext_vector_type(4))) float f32x4;
typedef __attribute__((ext_vector_type(8))) short bf16x8;
typedef __attribute__((ext_vector_type(4))) short bf16x4;

#define NL 6

static __device__ __forceinline__ unsigned short f2bf(float f) {
    __hip_bfloat16 h = __float2bfloat16(f);
    return *reinterpret_cast<unsigned short*>(&h);
}
static __device__ __forceinline__ float bf2f(unsigned short u) {
    union { unsigned int u32; float f; } c; c.u32 = ((unsigned int)u) << 16; return c.f;
}
static __device__ __forceinline__ float gelu_exact(float v) {
    return 0.5f * v * (1.0f + erff(v * 0.70710678118654752f));
}
static __device__ __forceinline__ void gload_lds16(const void* g, void* l) {
    __builtin_amdgcn_global_load_lds((const __attribute__((address_space(1))) void*)g,
                                     (__attribute__((address_space(3))) void*)l, 16, 0, 0);
}

// ============================ GEMM ============================
// C[M,N] = alpha * A[M,K] @ B^T[N,K] (+bias)(gelu)(+rel-bias), A/B bf16.
// M % BM == 0. N guarded. K handled via nkt (k-tiles of 32) + skN split-K.
// SPART: write f32 partial to C + sk*pStride (no bias/act).
template<int BM, int BN, bool OBF, bool BIAS, bool GACT, bool RELB, bool SPART>
__global__ __launch_bounds__(256)
void gemm3(const unsigned short* __restrict__ A, const unsigned short* __restrict__ B,
           void* __restrict__ C, const float* __restrict__ bias,
           const unsigned short* __restrict__ rel,
           int M, int N, int nkt, int skN, int lda, int ldb, int ldc, float alpha,
           int modA, long sA1, long sA2, int modB, long sB1, long sB2,
           int modC, long sC1, long sC2, int biasStride, long pStride)
{
    constexpr int MI = BM / 32, NI = BN / 32;
    constexpr int ACH = BM / 16, NCH = (BM + BN) / 16;
    __shared__ __attribute__((aligned(16))) unsigned short Ls[(BM + BN) * 32];

    const int bz = blockIdx.z;
    const int sk = SPART ? (bz % skN) : 0;
    const int z  = SPART ? (bz / skN) : bz;
    const unsigned short* Ab = A + (long)(z % modA) * sA1 + (long)(z / modA) * sA2;
    const unsigned short* Bb = B + (long)(z % modB) * sB1 + (long)(z / modB) * sB2;
    const long offC = (long)(z % modC) * sC1 + (long)(z / modC) * sC2;

    const int bm0 = blockIdx.x * BM, bn0 = blockIdx.y * BN;
    const int t = threadIdx.x, lane = t & 63, w = t >> 6;
    const int wm = (w >> 1) * (BM / 2), wn = (w & 1) * (BN / 2);
    const int crow = lane >> 2, cs = lane & 3;
    const int fr = lane & 15, kq = lane >> 4;
    const int kBase = sk * nkt * 32;

    f32x4 acc[MI][NI];
    #pragma unroll
    for (int a = 0; a < MI; a++)
        #pragma unroll
        for (int b = 0; b < NI; b++) acc[a][b] = (f32x4){0.f, 0.f, 0.f, 0.f};

    for (int kt = 0; kt < nkt; ++kt) {
        const int k0 = kBase + (kt << 5);
        #pragma unroll
        for (int c0 = 0; c0 < NCH; c0 += 4) {
            int c = c0 + w;
            if (c < NCH) {
                const unsigned short* gp;
                if (c < ACH) {
                    int rit = c * 16 + crow;
                    int ks = cs ^ (rit & 3);
                    gp = Ab + (long)(bm0 + rit) * lda + k0 + ks * 8;
                } else {
                    int rit = (c - ACH) * 16 + crow;
                    int ks = cs ^ (rit & 3);
                    gp = Bb + (long)(bn0 + rit) * ldb + k0 + ks * 8;
                }
                gload_lds16(gp, &Ls[c * 512]);
            }
        }
        __syncthreads();
        bf16x8 af[MI], bfr[NI];
        #pragma unroll
        for (int mi = 0; mi < MI; mi++) {
            int R = wm + mi * 16 + fr;
            af[mi] = *(const bf16x8*)&Ls[R * 32 + ((kq ^ (R & 3)) << 3)];
        }
        #pragma unroll
        for (int ni = 0; ni < NI; ni++) {
            int Rb = wn + ni * 16 + fr;
            bfr[ni] = *(const bf16x8*)&Ls[BM * 32 + Rb * 32 + ((kq ^ (Rb & 3)) << 3)];
        }
        #pragma unroll
        for (int mi = 0; mi < MI; mi++)
            #pragma unroll
            for (int ni = 0; ni < NI; ni++)
                acc[mi][ni] = __builtin_amdgcn_mfma_f32_16x16x32_bf16(af[mi], bfr[ni], acc[mi][ni], 0, 0, 0);
        __syncthreads();
    }

    const int q4 = (lane >> 4) << 2;
    if (SPART) {
        float* P = (float*)C + sk * pStride + offC;
        #pragma unroll
        for (int mi = 0; mi < MI; mi++)
            #pragma unroll
            for (int ni = 0; ni < NI; ni++)
                #pragma unroll
                for (int j = 0; j < 4; j++) {
                    int gr = bm0 + wm + mi * 16 + q4 + j;
                    int gc = bn0 + wn + ni * 16 + fr;
                    if (gc < N) P[(long)gr * ldc + gc] = acc[mi][ni][j] * alpha;
                }
    } else {
        float* Cf = (float*)C + offC;
        unsigned short* Ch = (unsigned short*)C + offC;
        const float* bp = BIAS ? (bias + (long)z * biasStride) : nullptr;
        const int rb_ = RELB ? (z >> 3) : 0, rh_ = RELB ? (z & 7) : 0;
        #pragma unroll
        for (int mi = 0; mi < MI; mi++)
            #pragma unroll
            for (int ni = 0; ni < NI; ni++)
                #pragma unroll
                for (int j = 0; j < 4; j++) {
                    int gr = bm0 + wm + mi * 16 + q4 + j;
                    int gc = bn0 + wn + ni * 16 + fr;
                    if (gc < N) {
                        float v = acc[mi][ni][j] * alpha;
                        if (RELB)
                            v += bf2f(rel[((long)((rb_ * 512 + gr) * 8 + rh_)) * 1025 + 512 - gr + gc]);
                        if (BIAS) v += bp[gc];
                        if (GACT) v = gelu_exact(v);
                        if (OBF) Ch[(long)gr * ldc + gc] = f2bf(v);
                        else     Cf[(long)gr * ldc + gc] = v;
                    }
                }
    }
}

// ============================ split-K reduce ============================
template<int SK, bool BIAS, bool FOUT, bool OBF>
__global__ __launch_bounds__(256)
void reduce_k(const float* __restrict__ parts, const float* __restrict__ bias,
              float* __restrict__ of, unsigned short* __restrict__ ob,
              int ncmask, long pStride)
{
    long i4 = ((long)blockIdx.x * 256 + threadIdx.x) * 4;
    float4 s = *(const float4*)(parts + i4);
    #pragma unroll
    for (int k = 1; k < SK; k++) {
        float4 p = *(const float4*)(parts + k * pStride + i4);
        s.x += p.x; s.y += p.y; s.z += p.z; s.w += p.w;
    }
    if (BIAS) {
        int c = (int)(i4 & ncmask);
        float4 bv = *(const float4*)(bias + c);
        s.x += bv.x; s.y += bv.y; s.z += bv.z; s.w += bv.w;
    }
    if (FOUT) *(float4*)(of + i4) = s;
    if (OBF) {
        bf16x4 o = {(short)f2bf(s.x), (short)f2bf(s.y), (short)f2bf(s.z), (short)f2bf(s.w)};
        *(bf16x4*)(ob + i4) = o;
    }
}

// =================== transpose-cast f32 -> bf16^T ===================
__global__ __launch_bounds__(256)
void trcast_k(const float* __restrict__ in, unsigned short* __restrict__ out,
              int R, int C, int Rp, long inStride, long outStride)
{
    __shared__ unsigned short tile[32][33];
    const int z = blockIdx.z;
    const float* ip = in + (long)z * inStride;
    unsigned short* op = out + (long)z * outStride;
    const int c0 = blockIdx.x * 32, r0 = blockIdx.y * 32;
    const int tx = threadIdx.x & 31, ty = threadIdx.x >> 5;
    #pragma unroll
    for (int q = 0; q < 4; q++) {
        int r = r0 + ty + q * 8;
        float v = (r < R) ? ip[(long)r * C + c0 + tx] : 0.f;
        tile[ty + q * 8][tx] = f2bf(v);
    }
    __syncthreads();
    #pragma unroll
    for (int q = 0; q < 4; q++) {
        int c = c0 + ty + q * 8;
        op[(long)c * Rp + r0 + tx] = tile[tx][ty + q * 8];
    }
}

// =================== cast (+row-pad) f32 -> bf16 ===================
__global__ __launch_bounds__(256)
void castpad_k(const float* __restrict__ in, unsigned short* __restrict__ out,
               int R, int C, long inStride, long outStride, long nPerZ)
{
    const int z = blockIdx.z;
    for (long idx = (long)blockIdx.x * 256 + threadIdx.x; idx < nPerZ;
         idx += (long)gridDim.x * 256) {
        int r = (int)(idx / C);
        float v = (r < R) ? in[(long)z * inStride + idx] : 0.f;
        out[(long)z * outStride + idx] = f2bf(v);
    }
}

// =================== V transpose: QKV cols 1024+ -> [32][64][512] ===================
__global__ __launch_bounds__(256)
void transp_v(const unsigned short* __restrict__ v, unsigned short* __restrict__ vt, int ldv)
{
    __shared__ unsigned short tile[32][33];
    const int b = blockIdx.z;
    const int j0 = blockIdx.x * 32, c0 = blockIdx.y * 32;
    const int tx = threadIdx.x & 31, ty = threadIdx.x >> 5;
    #pragma unroll
    for (int q = 0; q < 4; q++)
        tile[ty + q * 8][tx] = v[(long)(b * 512 + j0 + ty + q * 8) * ldv + c0 + tx];
    __syncthreads();
    #pragma unroll
    for (int q = 0; q < 4; q++) {
        int c = c0 + ty + q * 8;
        int h = c >> 6, d = c & 63;
        vt[((long)(b * 8 + h) * 64 + d) * 512 + j0 + tx] = tile[tx][ty + q * 8];
    }
}

// =================== softmax (bias already in SC) + AR build ===================
__global__ __launch_bounds__(256)
void softmax_ar(const float* __restrict__ sc, unsigned short* __restrict__ p,
                unsigned short* __restrict__ ar)
{
    __shared__ unsigned short rows[4][512];
    const int wv = threadIdx.x >> 6, lane = threadIdx.x & 63;
    const long row = (long)blockIdx.x * 4 + wv;
    const int b = (int)(row >> 12), h = (int)((row >> 9) & 7), i = (int)(row & 511);
    const int base = lane * 8;
    const float* sp = sc + row * 512 + base;
    float v[8];
    {
        float4 a0 = *(const float4*)sp, a1 = *(const float4*)(sp + 4);
        v[0] = a0.x; v[1] = a0.y; v[2] = a0.z; v[3] = a0.w;
        v[4] = a1.x; v[5] = a1.y; v[6] = a1.z; v[7] = a1.w;
    }
    float mx = -1e30f;
    #pragma unroll
    for (int jj = 0; jj < 8; jj++) mx = fmaxf(mx, v[jj]);
    #pragma unroll
    for (int off = 32; off; off >>= 1) mx = fmaxf(mx, __shfl_xor(mx, off));
    float s = 0.f;
    #pragma unroll
    for (int jj = 0; jj < 8; jj++) { v[jj] = __expf(v[jj] - mx); s += v[jj]; }
    #pragma unroll
    for (int off = 32; off; off >>= 1) s += __shfl_xor(s, off);
    float inv = 1.f / s;
    bf16x8 o;
    #pragma unroll
    for (int jj = 0; jj < 8; jj++) o[jj] = (short)f2bf(v[jj] * inv);
    *(bf16x8*)(p + row * 512 + base) = o;
    *(bf16x8*)&rows[wv][base] = o;
    // AR row: m = (b*512+i)*8+h, ar[m][r] = P[i][i + r - 512]
    const long m = ((long)(b * 512 + i) * 8 + h);
    unsigned short* dst = ar + m * 1056;
    const int sh = 512 - i;
    for (int rb = lane; rb < 132; rb += 64) {
        int r0 = rb * 8;
        bf16x8 ov;
        #pragma unroll
        for (int e = 0; e < 8; e++) {
            int j = r0 + e - sh;
            ov[e] = ((unsigned)j < 512u) ? (short)rows[wv][j] : (short)0;
        }
        *(bf16x8*)(dst + r0) = ov;
    }
}

// =================== fused double LN: y = LN2(x + LN1(o + x)) ===================
__global__ __launch_bounds__(256)
void ln2x_k(const float* __restrict__ o1, const float* __restrict__ x,
            const float* __restrict__ g1, const float* __restrict__ b1,
            const float* __restrict__ g2, const float* __restrict__ b2,
            float* __restrict__ yf, unsigned short* __restrict__ yb)
{
    const int wv = threadIdx.x >> 6, lane = threadIdx.x & 63;
    const long row = (long)blockIdx.x * 4 + wv;
    const int base = lane * 8;
    const float* po = o1 + row * 512 + base;
    const float* px = x + row * 512 + base;
    float xv[8], v[8];
    {
        float4 x0 = *(const float4*)px, x1 = *(const float4*)(px + 4);
        float4 o0 = *(const float4*)po, o1v = *(const float4*)(po + 4);
        xv[0] = x0.x; xv[1] = x0.y; xv[2] = x0.z; xv[3] = x0.w;
        xv[4] = x1.x; xv[5] = x1.y; xv[6] = x1.z; xv[7] = x1.w;
        v[0] = xv[0] + o0.x; v[1] = xv[1] + o0.y; v[2] = xv[2] + o0.z; v[3] = xv[3] + o0.w;
        v[4] = xv[4] + o1v.x; v[5] = xv[5] + o1v.y; v[6] = xv[6] + o1v.z; v[7] = xv[7] + o1v.w;
    }
    float s = 0.f;
    #pragma unroll
    for (int jj = 0; jj < 8; jj++) s += v[jj];
    #pragma unroll
    for (int off = 32; off; off >>= 1) s += __shfl_xor(s, off);
    float mean = s * (1.f / 512.f);
    float vs = 0.f;
    #pragma unroll
    for (int jj = 0; jj < 8; jj++) { float d = v[jj] - mean; vs += d * d; }
    #pragma unroll
    for (int off = 32; off; off >>= 1) vs += __shfl_xor(vs, off);
    float inv = rsqrtf(vs * (1.f / 512.f) + 1e-5f);
    float4 ga = *(const float4*)(g1 + base), gb = *(const float4*)(g1 + base + 4);
    float4 ba = *(const float4*)(b1 + base), bb = *(const float4*)(b1 + base + 4);
    float gg[8] = {ga.x, ga.y, ga.z, ga.w, gb.x, gb.y, gb.z, gb.w};
    float ee[8] = {ba.x, ba.y, ba.z, ba.w, bb.x, bb.y, bb.z, bb.w};
    float tvec[8];
    #pragma unroll
    for (int jj = 0; jj < 8; jj++) tvec[jj] = xv[jj] + (v[jj] - mean) * inv * gg[jj] + ee[jj];
    // second LN
    float s2 = 0.f;
    #pragma unroll
    for (int jj = 0; jj < 8; jj++) s2 += tvec[jj];
    #pragma unroll
    for (int off = 32; off; off >>= 1) s2 += __shfl_xor(s2, off);
    float m2 = s2 * (1.f / 512.f);
    float vs2 = 0.f;
    #pragma unroll
    for (int jj = 0; jj < 8; jj++) { float d = tvec[jj] - m2; vs2 += d * d; }
    #pragma unroll
    for (int off = 32; off; off >>= 1) vs2 += __shfl_xor(vs2, off);
    float inv2 = rsqrtf(vs2 * (1.f / 512.f) + 1e-5f);
    float4 gc = *(const float4*)(g2 + base), gd = *(const float4*)(g2 + base + 4);
    float4 bc = *(const float4*)(b2 + base), bd = *(const float4*)(b2 + base + 4);
    float g2v[8] = {gc.x, gc.y, gc.z, gc.w, gd.x, gd.y, gd.z, gd.w};
    float b2v[8] = {bc.x, bc.y, bc.z, bc.w, bd.x, bd.y, bd.z, bd.w};
    float r[8];
    #pragma unroll
    for (int jj = 0; jj < 8; jj++) r[jj] = (tvec[jj] - m2) * inv2 * g2v[jj] + b2v[jj];
    float* pf = yf + row * 512 + base;
    *(float4*)pf = (float4){r[0], r[1], r[2], r[3]};
    *(float4*)(pf + 4) = (float4){r[4], r[5], r[6], r[7]};
    bf16x8 ov;
    #pragma unroll
    for (int jj = 0; jj < 8; jj++) ov[jj] = (short)f2bf(r[jj]);
    *(bf16x8*)(yb + row * 512 + base) = ov;
}

// =================== LN(a+b): f32 out + bf16 out ===================
__global__ __launch_bounds__(256)
void ln_add2(const float* __restrict__ a, const float* __restrict__ b2,
             const float* __restrict__ g, const float* __restrict__ be,
             float* __restrict__ o, unsigned short* __restrict__ ob)
{
    const int wv = threadIdx.x >> 6, lane = threadIdx.x & 63;
    const long row = (long)blockIdx.x * 4 + wv;
    const int base = lane * 8;
    const float* pa = a + row * 512 + base;
    const float* pb = b2 + row * 512 + base;
    float v[8];
    {
        float4 x0 = *(const float4*)pa, x1 = *(const float4*)(pa + 4);
        float4 y0 = *(const float4*)pb, y1 = *(const float4*)(pb + 4);
        v[0] = x0.x + y0.x; v[1] = x0.y + y0.y; v[2] = x0.z + y0.z; v[3] = x0.w + y0.w;
        v[4] = x1.x + y1.x; v[5] = x1.y + y1.y; v[6] = x1.z + y1.z; v[7] = x1.w + y1.w;
    }
    float s = 0.f;
    #pragma unroll
    for (int jj = 0; jj < 8; jj++) s += v[jj];
    #pragma unroll
    for (int off = 32; off; off >>= 1) s += __shfl_xor(s, off);
    float mean = s * (1.f / 512.f);
    float vs = 0.f;
    #pragma unroll
    for (int jj = 0; jj < 8; jj++) { float d = v[jj] - mean; vs += d * d; }
    #pragma unroll
    for (int off = 32; off; off >>= 1) vs += __shfl_xor(vs, off);
    float inv = rsqrtf(vs * (1.f / 512.f) + 1e-5f);
    float4 g0 = *(const float4*)(g + base), g1 = *(const float4*)(g + base + 4);
    float4 e0 = *(const float4*)(be + base), e1 = *(const float4*)(be + base + 4);
    float gg[8] = {g0.x, g0.y, g0.z, g0.w, g1.x, g1.y, g1.z, g1.w};
    float ee[8] = {e0.x, e0.y, e0.z, e0.w, e1.x, e1.y, e1.z, e1.w};
    float r[8];
    #pragma unroll
    for (int jj = 0; jj < 8; jj++) r[jj] = (v[jj] - mean) * inv * gg[jj] + ee[jj];
    float* po = o + row * 512 + base;
    *(float4*)po = (float4){r[0], r[1], r[2], r[3]};
    *(float4*)(po + 4) = (float4){r[4], r[5], r[6], r[7]};
    bf16x8 ov;
    #pragma unroll
    for (int jj = 0; jj < 8; jj++) ov[jj] = (short)f2bf(r[jj]);
    *(bf16x8*)(ob + row * 512 + base) = ov;
}

// =================== seasonal combine ===================
__global__ __launch_bounds__(256)
void combine2(const float* __restrict__ tr, const float* __restrict__ rs,
              const float* __restrict__ se, const float* __restrict__ comb,
              float* __restrict__ xo, unsigned short* __restrict__ xb)
{
    float c[5]; float m = -1e30f;
    #pragma unroll
    for (int k = 0; k < 5; k++) { c[k] = comb[k]; m = fmaxf(m, c[k]); }
    float s = 0.f;
    #pragma unroll
    for (int k = 0; k < 5; k++) { c[k] = __expf(c[k] - m); s += c[k]; }
    float inv = 1.f / s;
    long i4 = ((long)blockIdx.x * 256 + threadIdx.x) * 4;
    float4 t = *(const float4*)(tr + i4);
    float4 r = *(const float4*)(rs + i4);
    float4 s0 = *(const float4*)(se + i4);
    float4 s1 = *(const float4*)(se + 1048576 + i4);
    float4 s2 = *(const float4*)(se + 2097152 + i4);
    float o[4];
    o[0] = inv * (c[0] * t.x + c[4] * r.x + c[1] * s0.x + c[2] * s1.x + c[3] * s2.x);
    o[1] = inv * (c[0] * t.y + c[4] * r.y + c[1] * s0.y + c[2] * s1.y + c[3] * s2.y);
    o[2] = inv * (c[0] * t.z + c[4] * r.z + c[1] * s0.z + c[2] * s1.z + c[3] * s2.z);
    o[3] = inv * (c[0] * t.w + c[4] * r.w + c[1] * s0.w + c[2] * s1.w + c[3] * s2.w);
    *(float4*)(xo + i4) = (float4){o[0], o[1], o[2], o[3]};
    bf16x4 ov = {(short)f2bf(o[0]), (short)f2bf(o[1]), (short)f2bf(o[2]), (short)f2bf(o[3])};
    *(bf16x4*)(xb + i4) = ov;
}

// ============================ host ============================
#define G3(BM,BN,OBF,BIAS,GACT,RELB,SPART, A,B,C,bias_,rel_, M,N,NKT,SKN, lda,ldb,ldc, alpha, mA,a1,a2, mB,b1,b2, mC,c1,c2, bstr, pstr, Zg) \
    gemm3<BM,BN,OBF,BIAS,GACT,RELB,SPART><<<dim3((M)/(BM), ((N)+(BN)-1)/(BN), (Zg)), dim3(256), 0, stream>>>( \
        (A),(B),(C),(bias_),(rel_),(M),(N),(NKT),(SKN),(lda),(ldb),(ldc),(alpha), \
        (mA),(long)(a1),(long)(a2),(mB),(long)(b1),(long)(b2),(mC),(long)(c1),(long)(c2),(bstr),(long)(pstr))

extern "C" void kernel_launch(void* const* d_in, const int* in_sizes, int n_in,
                              void* d_out, int out_size, void* d_ws, size_t ws_size,
                              hipStream_t stream)
{
    (void)in_sizes; (void)n_in; (void)out_size; (void)ws_size;
    const float* x    = (const float*)d_in[0];
    const float* t1w  = (const float*)d_in[1];
    const float* t1b  = (const float*)d_in[2];
    const float* t2w  = (const float*)d_in[3];
    const float* t2b  = (const float*)d_in[4];
    const float* s1w  = (const float*)d_in[5];
    const float* s1b  = (const float*)d_in[6];
    const float* s2w  = (const float*)d_in[7];
    const float* s2b  = (const float*)d_in[8];
    const float* r1w  = (const float*)d_in[9];
    const float* r1b  = (const float*)d_in[10];
    const float* r2w  = (const float*)d_in[11];
    const float* r2b  = (const float*)d_in[12];
    const float* comb = (const float*)d_in[13];
    const float* wq   = (const float*)d_in[14];
    const float* wk   = (const float*)d_in[15];
    const float* wvv  = (const float*)d_in[16];
    const float* wow  = (const float*)d_in[17];
    const float* wob  = (const float*)d_in[18];
    const float* relk = (const float*)d_in[19];
    const float* relv = (const float*)d_in[20];
    const float* lag  = (const float*)d_in[21];
    const float* labi = (const float*)d_in[22];
    const float* f1w  = (const float*)d_in[23];
    const float* f1b  = (const float*)d_in[24];
    const float* f2w  = (const float*)d_in[25];
    const float* f2b  = (const float*)d_in[26];
    const float* n1g  = (const float*)d_in[27];
    const float* n1b  = (const float*)d_in[28];
    const float* n2g  = (const float*)d_in[29];
    const float* n2b  = (const float*)d_in[30];

    char* ws = (char*)d_ws;
    #define OFFK(kb) (ws + (size_t)(kb) * 1024)
    float* X    = (float*)OFFK(0);          // 4MB [2048][512]
    float* T1   = (float*)OFFK(4096);       // 4MB
    float* T3   = (float*)OFFK(8192);       // 4MB
    float* SC   = (float*)OFFK(12288);      // 32MB f32 [32][512][512]
    float* PART = (float*)OFFK(12288);      // alias: 20MB [5][2048][512] f32 partials
    float* SEAS = (float*)OFFK(12288);      // alias: prologue 12MB
    float* T2   = (float*)OFFK(24576);      // alias in SC region (prologue only)
    unsigned short* Xb   = (unsigned short*)OFFK(45056);  // 2MB
    unsigned short* Xb0  = (unsigned short*)OFFK(47104);  // 2MB
    unsigned short* QKVb = (unsigned short*)OFFK(49152);  // 6MB [2048][1536]
    unsigned short* VT   = (unsigned short*)OFFK(55296);  // 2MB [32][64][512]
    unsigned short* CTXb = (unsigned short*)OFFK(57344);  // 2MB
    unsigned short* T3b  = (unsigned short*)OFFK(59392);  // 2MB
    unsigned short* FFb  = (unsigned short*)OFFK(61440);  // 8MB [2048][2048]
    unsigned short* SCb  = (unsigned short*)OFFK(69632);  // 16MB [32][512][512]
    unsigned short* QR   = (unsigned short*)OFFK(86016);  // 32.8MB [2048][8][1025]
    unsigned short* AR   = (unsigned short*)OFFK(86016);  // alias: 33.8MB [16384][1056]
    unsigned short* SHb  = (unsigned short*)OFFK(86016);  // alias (prologue): [3][2048][256]
    unsigned short* qkvT = (unsigned short*)OFFK(119808); // 9MB [6][1536][512]
    unsigned short* woT  = (unsigned short*)OFFK(129024); // 3MB
    unsigned short* f1wT = (unsigned short*)OFFK(132096); // 12MB
    unsigned short* f2wT = (unsigned short*)OFFK(144384); // 12MB
    unsigned short* relkb= (unsigned short*)OFFK(156672); // [6][1088][64]
    unsigned short* rvT  = (unsigned short*)OFFK(157488); // [6][64][1056]
    unsigned short* t1wT = (unsigned short*)OFFK(158280);
    unsigned short* t2wT = (unsigned short*)OFFK(158792);
    unsigned short* r1wT = (unsigned short*)OFFK(159304);
    unsigned short* r2wT = (unsigned short*)OFFK(159560);
    unsigned short* s1wT = (unsigned short*)OFFK(159816);
    unsigned short* s2wT = (unsigned short*)OFFK(160584);

    // ---------------- prep: casts + transposes ----------------
    castpad_k<<<dim3(1024, 1, 1), 256, 0, stream>>>(x, Xb0, 2048, 512, 1048576, 1048576, 1048576);
    trcast_k<<<dim3(16, 16, 1), 256, 0, stream>>>(t1w, t1wT, 512, 512, 512, 262144, 262144);
    trcast_k<<<dim3(16, 16, 1), 256, 0, stream>>>(t2w, t2wT, 512, 512, 512, 262144, 262144);
    trcast_k<<<dim3(8, 16, 1), 256, 0, stream>>>(r1w, r1wT, 512, 256, 512, 131072, 131072);
    trcast_k<<<dim3(16, 8, 1), 256, 0, stream>>>(r2w, r2wT, 256, 512, 256, 131072, 131072);
    trcast_k<<<dim3(8, 16, 3), 256, 0, stream>>>(s1w, s1wT, 512, 256, 512, 131072, 131072);
    trcast_k<<<dim3(16, 8, 3), 256, 0, stream>>>(s2w, s2wT, 256, 512, 256, 131072, 131072);
    trcast_k<<<dim3(16, 16, 6), 256, 0, stream>>>(wq,  qkvT,          512, 512, 512, 262144, 786432);
    trcast_k<<<dim3(16, 16, 6), 256, 0, stream>>>(wk,  qkvT + 262144, 512, 512, 512, 262144, 786432);
    trcast_k<<<dim3(16, 16, 6), 256, 0, stream>>>(wvv, qkvT + 524288, 512, 512, 512, 262144, 786432);
    trcast_k<<<dim3(16, 16, 6), 256, 0, stream>>>(wow, woT, 512, 512, 512, 262144, 262144);
    trcast_k<<<dim3(64, 16, 6), 256, 0, stream>>>(f1w, f1wT, 512, 2048, 512, 1048576, 1048576);
    trcast_k<<<dim3(16, 64, 6), 256, 0, stream>>>(f2w, f2wT, 2048, 512, 2048, 1048576, 1048576);
    trcast_k<<<dim3(2, 33, 6), 256, 0, stream>>>(relv, rvT, 1025, 64, 1056, 65600, 67584);
    castpad_k<<<dim3(272, 1, 6), 256, 0, stream>>>(relk, relkb, 1025, 64, 65600, 69632, 69632);

    // ---------------- seasonal decomposition ----------------
    G3(64,64,true,true,true,false,false,   Xb0, t1wT, T3b,  t1b, nullptr, 2048,512,16,1, 512,512,512, 1.f, 1,0,0, 1,0,0, 1,0,0, 0,0, 1);
    G3(64,64,false,true,false,false,false, T3b, t2wT, T1,   t2b, nullptr, 2048,512,16,1, 512,512,512, 1.f, 1,0,0, 1,0,0, 1,0,0, 0,0, 1);
    G3(64,64,true,true,true,false,false,   Xb0, r1wT, CTXb, r1b, nullptr, 2048,256,16,1, 512,512,256, 1.f, 1,0,0, 1,0,0, 1,0,0, 0,0, 1);
    G3(64,64,false,true,false,false,false, CTXb,r2wT, T2,   r2b, nullptr, 2048,512,8,1,  256,256,512, 1.f, 1,0,0, 1,0,0, 1,0,0, 0,0, 1);
    G3(64,64,true,true,true,false,false,   Xb0, s1wT, SHb,  s1b, nullptr, 2048,256,16,1, 512,512,256, 1.f, 1,0,0, 3,131072,0, 3,524288,0, 256,0, 3);
    G3(64,64,false,true,false,false,false, SHb, s2wT, SEAS, s2b, nullptr, 2048,512,8,1,  256,256,512, 1.f, 3,524288,0, 3,131072,0, 3,1048576,0, 512,0, 3);
    combine2<<<dim3(1024), 256, 0, stream>>>(T1, T2, SEAS, comb, X, Xb);

    // ---------------- transformer layers ----------------
    for (int l = 0; l < NL; ++l) {
        const unsigned short* qkvTl = qkvT + (long)l * 786432;
        const unsigned short* woTl  = woT + (long)l * 262144;
        const unsigned short* f1Tl  = f1wT + (long)l * 1048576;
        const unsigned short* f2Tl  = f2wT + (long)l * 1048576;
        const unsigned short* rkl   = relkb + (long)l * 69632;
        const unsigned short* rvl   = rvT + (long)l * 67584;

        // QKV (merged)
        G3(64,64,true,false,false,false,false, Xb, qkvTl, QKVb, nullptr, nullptr, 2048,1536,16,1, 512,512,1536, 1.f,
           1,0,0, 1,0,0, 1,0,0, 0,0, 1);
        transp_v<<<dim3(16, 16, 4), 256, 0, stream>>>(QKVb + 1024, VT, 1536);
        // qrel[bi][h][r] = Q . rel_k_r  (batched over h)
        G3(64,64,true,false,false,false,false, QKVb, rkl, QR, nullptr, nullptr, 2048,1025,2,1, 1536,64,8200, 1.f,
           8,64,0, 1,0,0, 8,1025,0, 0,0, 8);
        // scores = 0.125*Q@K^T + gather(qrel)   (batched over bh)
        G3(64,64,false,false,false,true,false, QKVb, QKVb + 512, SC, nullptr, QR, 512,512,2,1, 1536,1536,512, 0.125f,
           8,64,786432, 8,64,786432, 1,0,262144, 0,0, 32);
        softmax_ar<<<dim3(4096), 256, 0, stream>>>(SC, SCb, AR);
        // ctx partials: P@V (sk 0-1) and AR@rel_v^T (sk 2-4)
        G3(64,64,false,false,false,false,true, SCb, VT, PART, nullptr, nullptr, 512,64,8,2, 512,512,512, 1.f,
           1,0,262144, 1,0,32768, 8,64,262144, 0,1048576, 64);
        G3(64,64,false,false,false,false,true, AR, rvl, PART + 2097152, nullptr, nullptr, 16384,64,11,3, 1056,1056,64, 1.f,
           1,0,0, 1,0,0, 1,0,0, 0,1048576, 3);
        reduce_k<5,false,false,true><<<dim3(1024), 256, 0, stream>>>(PART, nullptr, nullptr, CTXb, 511, 1048576);
        // out = ctx @ wo + b
        G3(64,64,false,true,false,false,false, CTXb, woTl, T1, wob + l * 512, nullptr, 2048,512,16,1, 512,512,512, 1.f,
           1,0,0, 1,0,0, 1,0,0, 0,0, 1);
        // y1 = LN(x + LN(out + x))
        ln2x_k<<<dim3(512), 256, 0, stream>>>(T1, X, lag + l * 512, labi + l * 512,
                                              n1g + l * 512, n1b + l * 512, T3, T3b);
        // FF
        G3(64,64,true,true,true,false,false, T3b, f1Tl, FFb, f1b + l * 2048, nullptr, 2048,2048,16,1, 512,512,2048, 1.f,
           1,0,0, 1,0,0, 1,0,0, 0,0, 1);
        G3(64,64,false,false,false,false,true, FFb, f2Tl, PART, nullptr, nullptr, 2048,512,16,4, 2048,2048,512, 1.f,
           1,0,0, 1,0,0, 1,0,0, 0,1048576, 4);
        reduce_k<4,true,true,false><<<dim3(1024), 256, 0, stream>>>(PART, f2b + l * 512, T1, nullptr, 511, 1048576);
        // y = LN(y1 + ff)
        float* outp = (l == NL - 1) ? (float*)d_out : X;
        ln_add2<<<dim3(512), 256, 0, stream>>>(T3, T1, n2g + l * 512, n2b + l * 512, outp, Xb);
    }
}

// Round 4
// 739.537 us; speedup vs baseline: 3.4697x; 1.2259x over previous
//
#include <hip/hip_runtime.h>
#include <hip/hip_bf16.h>

typedef __attribute__((ext_vector_type(4))) float f32x4;
typedef __attribute__((ext_vector_type(8))) short bf16x8;
typedef __attribute__((ext_vector_type(4))) short bf16x4;

#define NL 6

static __device__ __forceinline__ unsigned short f2bf(float f) {
    __hip_bfloat16 h = __float2bfloat16(f);
    return *reinterpret_cast<unsigned short*>(&h);
}
static __device__ __forceinline__ float bf2f(unsigned short u) {
    union { unsigned int u32; float f; } c; c.u32 = ((unsigned int)u) << 16; return c.f;
}
static __device__ __forceinline__ float gelu_exact(float v) {
    return 0.5f * v * (1.0f + erff(v * 0.70710678118654752f));
}
static __device__ __forceinline__ void gload_lds16(const void* g, void* l) {
    __builtin_amdgcn_global_load_lds((const __attribute__((address_space(1))) void*)g,
                                     (__attribute__((address_space(3))) void*)l, 16, 0, 0);
}
static __device__ __forceinline__ f32x4 MF(bf16x8 a, bf16x8 b, f32x4 c) {
    return __builtin_amdgcn_mfma_f32_16x16x32_bf16(a, b, c, 0, 0, 0);
}

// ============================ GEMM ============================
// C[M,N] = alpha * A[M,K] @ B^T[N,K] (+bias)(gelu)(+rel-bias), A/B bf16.
template<int BM, int BN, bool OBF, bool BIAS, bool GACT, bool RELB, bool SPART>
__global__ __launch_bounds__(256)
void gemm3(const unsigned short* __restrict__ A, const unsigned short* __restrict__ B,
           void* __restrict__ C, const float* __restrict__ bias,
           const unsigned short* __restrict__ rel,
           int M, int N, int nkt, int skN, int lda, int ldb, int ldc, float alpha,
           int modA, long sA1, long sA2, int modB, long sB1, long sB2,
           int modC, long sC1, long sC2, int biasStride, long pStride)
{
    constexpr int MI = BM / 32, NI = BN / 32;
    constexpr int ACH = BM / 16, NCH = (BM + BN) / 16;
    __shared__ __attribute__((aligned(16))) unsigned short Ls[(BM + BN) * 32];

    const int bz = blockIdx.z;
    const int sk = SPART ? (bz % skN) : 0;
    const int z  = SPART ? (bz / skN) : bz;
    const unsigned short* Ab = A + (long)(z % modA) * sA1 + (long)(z / modA) * sA2;
    const unsigned short* Bb = B + (long)(z % modB) * sB1 + (long)(z / modB) * sB2;
    const long offC = (long)(z % modC) * sC1 + (long)(z / modC) * sC2;

    const int bm0 = blockIdx.x * BM, bn0 = blockIdx.y * BN;
    const int t = threadIdx.x, lane = t & 63, w = t >> 6;
    const int wm = (w >> 1) * (BM / 2), wn = (w & 1) * (BN / 2);
    const int crow = lane >> 2, cs = lane & 3;
    const int fr = lane & 15, kq = lane >> 4;
    const int kBase = sk * nkt * 32;

    f32x4 acc[MI][NI];
    #pragma unroll
    for (int a = 0; a < MI; a++)
        #pragma unroll
        for (int b = 0; b < NI; b++) acc[a][b] = (f32x4){0.f, 0.f, 0.f, 0.f};

    for (int kt = 0; kt < nkt; ++kt) {
        const int k0 = kBase + (kt << 5);
        #pragma unroll
        for (int c0 = 0; c0 < NCH; c0 += 4) {
            int c = c0 + w;
            if (c < NCH) {
                const unsigned short* gp;
                if (c < ACH) {
                    int rit = c * 16 + crow;
                    int ks = cs ^ (rit & 3);
                    gp = Ab + (long)(bm0 + rit) * lda + k0 + ks * 8;
                } else {
                    int rit = (c - ACH) * 16 + crow;
                    int ks = cs ^ (rit & 3);
                    gp = Bb + (long)(bn0 + rit) * ldb + k0 + ks * 8;
                }
                gload_lds16(gp, &Ls[c * 512]);
            }
        }
        __syncthreads();
        bf16x8 af[MI], bfr[NI];
        #pragma unroll
        for (int mi = 0; mi < MI; mi++) {
            int R = wm + mi * 16 + fr;
            af[mi] = *(const bf16x8*)&Ls[R * 32 + ((kq ^ (R & 3)) << 3)];
        }
        #pragma unroll
        for (int ni = 0; ni < NI; ni++) {
            int Rb = wn + ni * 16 + fr;
            bfr[ni] = *(const bf16x8*)&Ls[BM * 32 + Rb * 32 + ((kq ^ (Rb & 3)) << 3)];
        }
        #pragma unroll
        for (int mi = 0; mi < MI; mi++)
            #pragma unroll
            for (int ni = 0; ni < NI; ni++)
                acc[mi][ni] = MF(af[mi], bfr[ni], acc[mi][ni]);
        __syncthreads();
    }

    const int q4 = (lane >> 4) << 2;
    if (SPART) {
        float* P = (float*)C + sk * pStride + offC;
        #pragma unroll
        for (int mi = 0; mi < MI; mi++)
            #pragma unroll
            for (int ni = 0; ni < NI; ni++)
                #pragma unroll
                for (int j = 0; j < 4; j++) {
                    int gr = bm0 + wm + mi * 16 + q4 + j;
                    int gc = bn0 + wn + ni * 16 + fr;
                    if (gc < N) P[(long)gr * ldc + gc] = acc[mi][ni][j] * alpha;
                }
    } else {
        float* Cf = (float*)C + offC;
        unsigned short* Ch = (unsigned short*)C + offC;
        const float* bp = BIAS ? (bias + (long)z * biasStride) : nullptr;
        const int rb_ = RELB ? (z >> 3) : 0, rh_ = RELB ? (z & 7) : 0;
        #pragma unroll
        for (int mi = 0; mi < MI; mi++)
            #pragma unroll
            for (int ni = 0; ni < NI; ni++)
                #pragma unroll
                for (int j = 0; j < 4; j++) {
                    int gr = bm0 + wm + mi * 16 + q4 + j;
                    int gc = bn0 + wn + ni * 16 + fr;
                    if (gc < N) {
                        float v = acc[mi][ni][j] * alpha;
                        if (RELB)
                            v += bf2f(rel[((long)((rb_ * 512 + gr) * 8 + rh_)) * 1025 + 512 - gr + gc]);
                        if (BIAS) v += bp[gc];
                        if (GACT) v = gelu_exact(v);
                        if (OBF) Ch[(long)gr * ldc + gc] = f2bf(v);
                        else     Cf[(long)gr * ldc + gc] = v;
                    }
                }
    }
}

// ==================== fused flash attention with rel-pos ====================
// grid (8 i-tiles, 32 bh). Per block: Q-tile 64 rows, loop 8 KV-tiles.
// qkv [2048][1536]; vt [32][64][512]; qr [2048][8][1025] (ldr 8200);
// rvt layer's [64][1056]; ctx out bf16 [2048][512].
__global__ __launch_bounds__(256)
void fused_attn(const unsigned short* __restrict__ qkv,
                const unsigned short* __restrict__ vt,
                const unsigned short* __restrict__ qr,
                const unsigned short* __restrict__ rvt,
                unsigned short* __restrict__ ctx)
{
    // LDS map (shorts): Q 0..4096 | K 4096 | V 8192 | R 12288(8192) | P 20480(4096) | A 24576(8192)
    __shared__ __attribute__((aligned(16))) unsigned short L[32768];
    const int bh = blockIdx.y, b = bh >> 3, h = bh & 7;
    const int i0 = blockIdx.x * 64;
    const int t = threadIdx.x, lane = t & 63, wv = t >> 6;
    const int crow = lane >> 2, cs = lane & 3;
    const int fr = lane & 15, kq = lane >> 4;
    const int q4 = kq << 2;
    const int iiw = wv * 16;

    const unsigned short* Qg = qkv + ((long)(b * 512 + i0)) * 1536 + h * 64;
    const unsigned short* Kg = qkv + ((long)(b * 512)) * 1536 + 512 + h * 64;
    const unsigned short* Vg = vt + ((long)bh * 64) * 512;

    // stage Q once
    #pragma unroll
    for (int k = 0; k < 2; k++) {
        int c = wv + k * 4;
        int kt = c >> 2, row = (c & 3) * 16 + crow, ks = cs ^ (row & 3);
        gload_lds16(Qg + (long)row * 1536 + kt * 32 + ks * 8, &L[c * 512]);
    }
    __syncthreads();
    bf16x8 qf[2];
    {
        int r = iiw + fr;
        qf[0] = *(const bf16x8*)&L[r * 32 + ((kq ^ (r & 3)) << 3)];
        qf[1] = *(const bf16x8*)&L[2048 + r * 32 + ((kq ^ (r & 3)) << 3)];
    }

    f32x4 ctxa[4];
    #pragma unroll
    for (int ni = 0; ni < 4; ni++) ctxa[ni] = (f32x4){0.f, 0.f, 0.f, 0.f};
    float m_[4] = {-1e30f, -1e30f, -1e30f, -1e30f};
    float l_[4] = {0.f, 0.f, 0.f, 0.f};

    for (int jt = 0; jt < 8; ++jt) {
        const int j0 = jt * 64;
        const int rbase = j0 - i0 + 448;
        __syncthreads();   // prior step's LDS reads complete
        // stage K(8) V(8) RV(16) chunks
        #pragma unroll
        for (int k = 0; k < 8; k++) {
            int c = wv + k * 4;
            const unsigned short* gp;
            int dst;
            if (c < 8) {
                int kt = c >> 2, row = (c & 3) * 16 + crow, ks = cs ^ (row & 3);
                gp = Kg + (long)(j0 + row) * 1536 + kt * 32 + ks * 8;
                dst = 4096 + c * 512;
            } else if (c < 16) {
                int cc = c - 8;
                int kt = cc >> 2, row = (cc & 3) * 16 + crow, ks = cs ^ (row & 3);
                gp = Vg + (long)row * 512 + j0 + kt * 32 + ks * 8;
                dst = 8192 + cc * 512;
            } else {
                int cc = c - 16;
                int kt = cc >> 2, row = (cc & 3) * 16 + crow, ks = cs ^ (row & 3);
                gp = rvt + (long)row * 1056 + rbase + kt * 32 + ks * 8;
                dst = 12288 + cc * 512;
            }
            gload_lds16(gp, &L[dst]);
        }
        __syncthreads();
        // S = Q @ K^T
        f32x4 s[4];
        #pragma unroll
        for (int ni = 0; ni < 4; ni++) {
            int rB = ni * 16 + fr;
            bf16x8 b0 = *(const bf16x8*)&L[4096 + rB * 32 + ((kq ^ (rB & 3)) << 3)];
            bf16x8 b1 = *(const bf16x8*)&L[4096 + 2048 + rB * 32 + ((kq ^ (rB & 3)) << 3)];
            f32x4 a0 = (f32x4){0.f, 0.f, 0.f, 0.f};
            a0 = MF(qf[0], b0, a0);
            s[ni] = MF(qf[1], b1, a0);
        }
        // scale + rel-k bias gather (coalesced in fr)
        #pragma unroll
        for (int j = 0; j < 4; j++) {
            int il = iiw + q4 + j;
            const unsigned short* qp = qr + ((long)(b * 512 + i0 + il)) * 8200 + h * 1025
                                          + 512 + j0 - (i0 + il);
            #pragma unroll
            for (int ni = 0; ni < 4; ni++)
                s[ni][j] = s[ni][j] * 0.125f + bf2f(qp[ni * 16 + fr]);
        }
        // online softmax
        float mx[4];
        #pragma unroll
        for (int j = 0; j < 4; j++) {
            mx[j] = fmaxf(fmaxf(s[0][j], s[1][j]), fmaxf(s[2][j], s[3][j]));
            #pragma unroll
            for (int msk = 1; msk < 16; msk <<= 1) mx[j] = fmaxf(mx[j], __shfl_xor(mx[j], msk));
        }
        float scl[4];
        #pragma unroll
        for (int j = 0; j < 4; j++) {
            float mn = fmaxf(m_[j], mx[j]);
            scl[j] = __expf(m_[j] - mn);
            m_[j] = mn;
        }
        float rs[4] = {0.f, 0.f, 0.f, 0.f};
        #pragma unroll
        for (int ni = 0; ni < 4; ni++)
            #pragma unroll
            for (int j = 0; j < 4; j++) {
                float p = __expf(s[ni][j] - m_[j]);
                s[ni][j] = p;
                rs[j] += p;
            }
        #pragma unroll
        for (int j = 0; j < 4; j++) {
            #pragma unroll
            for (int msk = 1; msk < 16; msk <<= 1) rs[j] += __shfl_xor(rs[j], msk);
            l_[j] = l_[j] * scl[j] + rs[j];
        }
        #pragma unroll
        for (int ni = 0; ni < 4; ni++)
            #pragma unroll
            for (int j = 0; j < 4; j++) ctxa[ni][j] *= scl[j];
        // write P (for PV) and shifted AR (+paired zero) for rel-v
        #pragma unroll
        for (int ni = 0; ni < 4; ni++)
            #pragma unroll
            for (int j = 0; j < 4; j++) {
                int il = iiw + q4 + j;
                int jj = ni * 16 + fr;
                unsigned short pb = f2bf(s[ni][j]);
                L[20480 + il * 64 + (((jj >> 3) ^ (il & 7)) << 3) + (jj & 7)] = pb;
                int wI = jj - il + 64;           // in [1,127]
                L[24576 + il * 128 + (((wI >> 3) ^ (il & 7)) << 3) + (wI & 7)] = pb;
                int wz = (wI + 64) & 127;
                L[24576 + il * 128 + (((wz >> 3) ^ (il & 7)) << 3) + (wz & 7)] = 0;
            }
        // PV + AR@relv^T (wave-local P/A; no barrier needed)
        const int r = iiw + fr;
        bf16x8 pa0 = *(const bf16x8*)&L[20480 + r * 64 + (((kq) ^ (r & 7)) << 3)];
        bf16x8 pa1 = *(const bf16x8*)&L[20480 + r * 64 + (((4 + kq) ^ (r & 7)) << 3)];
        #pragma unroll
        for (int ni = 0; ni < 4; ni++) {
            int rB = ni * 16 + fr;
            bf16x8 vb0 = *(const bf16x8*)&L[8192 + rB * 32 + ((kq ^ (rB & 3)) << 3)];
            bf16x8 vb1 = *(const bf16x8*)&L[8192 + 2048 + rB * 32 + ((kq ^ (rB & 3)) << 3)];
            ctxa[ni] = MF(pa0, vb0, ctxa[ni]);
            ctxa[ni] = MF(pa1, vb1, ctxa[ni]);
        }
        #pragma unroll
        for (int kt = 0; kt < 4; kt++) {
            bf16x8 aa = *(const bf16x8*)&L[24576 + r * 128 + (((kt * 4 + kq) ^ (r & 7)) << 3)];
            #pragma unroll
            for (int ni = 0; ni < 4; ni++) {
                int rB = ni * 16 + fr;
                bf16x8 rb = *(const bf16x8*)&L[12288 + kt * 2048 + rB * 32 + ((kq ^ (rB & 3)) << 3)];
                ctxa[ni] = MF(aa, rb, ctxa[ni]);
            }
        }
    }
    // epilogue: ctx / l
    #pragma unroll
    for (int j = 0; j < 4; j++) {
        float inv = 1.f / l_[j];
        int il = iiw + q4 + j;
        unsigned short* op = ctx + ((long)(b * 512 + i0 + il)) * 512 + h * 64;
        #pragma unroll
        for (int ni = 0; ni < 4; ni++)
            op[ni * 16 + fr] = f2bf(ctxa[ni][j] * inv);
    }
}

// ============================ split-K reduce ============================
template<int SK, bool BIAS, bool FOUT, bool OBF>
__global__ __launch_bounds__(256)
void reduce_k(const float* __restrict__ parts, const float* __restrict__ bias,
              float* __restrict__ of, unsigned short* __restrict__ ob,
              int ncmask, long pStride)
{
    long i4 = ((long)blockIdx.x * 256 + threadIdx.x) * 4;
    float4 s = *(const float4*)(parts + i4);
    #pragma unroll
    for (int k = 1; k < SK; k++) {
        float4 p = *(const float4*)(parts + k * pStride + i4);
        s.x += p.x; s.y += p.y; s.z += p.z; s.w += p.w;
    }
    if (BIAS) {
        int c = (int)(i4 & ncmask);
        float4 bv = *(const float4*)(bias + c);
        s.x += bv.x; s.y += bv.y; s.z += bv.z; s.w += bv.w;
    }
    if (FOUT) *(float4*)(of + i4) = s;
    if (OBF) {
        bf16x4 o = {(short)f2bf(s.x), (short)f2bf(s.y), (short)f2bf(s.z), (short)f2bf(s.w)};
        *(bf16x4*)(ob + i4) = o;
    }
}

// =================== transpose-cast f32 -> bf16^T ===================
__global__ __launch_bounds__(256)
void trcast_k(const float* __restrict__ in, unsigned short* __restrict__ out,
              int R, int C, int Rp, long inStride, long outStride)
{
    __shared__ unsigned short tile[32][33];
    const int z = blockIdx.z;
    const float* ip = in + (long)z * inStride;
    unsigned short* op = out + (long)z * outStride;
    const int c0 = blockIdx.x * 32, r0 = blockIdx.y * 32;
    const int tx = threadIdx.x & 31, ty = threadIdx.x >> 5;
    #pragma unroll
    for (int q = 0; q < 4; q++) {
        int r = r0 + ty + q * 8;
        float v = (r < R) ? ip[(long)r * C + c0 + tx] : 0.f;
        tile[ty + q * 8][tx] = f2bf(v);
    }
    __syncthreads();
    #pragma unroll
    for (int q = 0; q < 4; q++) {
        int c = c0 + ty + q * 8;
        op[(long)c * Rp + r0 + tx] = tile[tx][ty + q * 8];
    }
}

// =================== cast (+row-pad) f32 -> bf16 ===================
__global__ __launch_bounds__(256)
void castpad_k(const float* __restrict__ in, unsigned short* __restrict__ out,
               int R, int C, long inStride, long outStride, long nPerZ)
{
    const int z = blockIdx.z;
    for (long idx = (long)blockIdx.x * 256 + threadIdx.x; idx < nPerZ;
         idx += (long)gridDim.x * 256) {
        int r = (int)(idx / C);
        float v = (r < R) ? in[(long)z * inStride + idx] : 0.f;
        out[(long)z * outStride + idx] = f2bf(v);
    }
}

// =================== V transpose: QKV cols 1024+ -> [32][64][512] ===================
__global__ __launch_bounds__(256)
void transp_v(const unsigned short* __restrict__ v, unsigned short* __restrict__ vt, int ldv)
{
    __shared__ unsigned short tile[32][33];
    const int b = blockIdx.z;
    const int j0 = blockIdx.x * 32, c0 = blockIdx.y * 32;
    const int tx = threadIdx.x & 31, ty = threadIdx.x >> 5;
    #pragma unroll
    for (int q = 0; q < 4; q++)
        tile[ty + q * 8][tx] = v[(long)(b * 512 + j0 + ty + q * 8) * ldv + c0 + tx];
    __syncthreads();
    #pragma unroll
    for (int q = 0; q < 4; q++) {
        int c = c0 + ty + q * 8;
        int h = c >> 6, d = c & 63;
        vt[((long)(b * 8 + h) * 64 + d) * 512 + j0 + tx] = tile[tx][ty + q * 8];
    }
}

// =================== fused double LN: y = LN2(x + LN1(o + x)) ===================
__global__ __launch_bounds__(256)
void ln2x_k(const float* __restrict__ o1, const float* __restrict__ x,
            const float* __restrict__ g1, const float* __restrict__ b1,
            const float* __restrict__ g2, const float* __restrict__ b2,
            float* __restrict__ yf, unsigned short* __restrict__ yb)
{
    const int wv = threadIdx.x >> 6, lane = threadIdx.x & 63;
    const long row = (long)blockIdx.x * 4 + wv;
    const int base = lane * 8;
    const float* po = o1 + row * 512 + base;
    const float* px = x + row * 512 + base;
    float xv[8], v[8];
    {
        float4 x0 = *(const float4*)px, x1 = *(const float4*)(px + 4);
        float4 o0 = *(const float4*)po, o1v = *(const float4*)(po + 4);
        xv[0] = x0.x; xv[1] = x0.y; xv[2] = x0.z; xv[3] = x0.w;
        xv[4] = x1.x; xv[5] = x1.y; xv[6] = x1.z; xv[7] = x1.w;
        v[0] = xv[0] + o0.x; v[1] = xv[1] + o0.y; v[2] = xv[2] + o0.z; v[3] = xv[3] + o0.w;
        v[4] = xv[4] + o1v.x; v[5] = xv[5] + o1v.y; v[6] = xv[6] + o1v.z; v[7] = xv[7] + o1v.w;
    }
    float s = 0.f;
    #pragma unroll
    for (int jj = 0; jj < 8; jj++) s += v[jj];
    #pragma unroll
    for (int off = 32; off; off >>= 1) s += __shfl_xor(s, off);
    float mean = s * (1.f / 512.f);
    float vs = 0.f;
    #pragma unroll
    for (int jj = 0; jj < 8; jj++) { float d = v[jj] - mean; vs += d * d; }
    #pragma unroll
    for (int off = 32; off; off >>= 1) vs += __shfl_xor(vs, off);
    float inv = rsqrtf(vs * (1.f / 512.f) + 1e-5f);
    float4 ga = *(const float4*)(g1 + base), gb = *(const float4*)(g1 + base + 4);
    float4 ba = *(const float4*)(b1 + base), bb = *(const float4*)(b1 + base + 4);
    float gg[8] = {ga.x, ga.y, ga.z, ga.w, gb.x, gb.y, gb.z, gb.w};
    float ee[8] = {ba.x, ba.y, ba.z, ba.w, bb.x, bb.y, bb.z, bb.w};
    float tvec[8];
    #pragma unroll
    for (int jj = 0; jj < 8; jj++) tvec[jj] = xv[jj] + (v[jj] - mean) * inv * gg[jj] + ee[jj];
    float s2 = 0.f;
    #pragma unroll
    for (int jj = 0; jj < 8; jj++) s2 += tvec[jj];
    #pragma unroll
    for (int off = 32; off; off >>= 1) s2 += __shfl_xor(s2, off);
    float m2 = s2 * (1.f / 512.f);
    float vs2 = 0.f;
    #pragma unroll
    for (int jj = 0; jj < 8; jj++) { float d = tvec[jj] - m2; vs2 += d * d; }
    #pragma unroll
    for (int off = 32; off; off >>= 1) vs2 += __shfl_xor(vs2, off);
    float inv2 = rsqrtf(vs2 * (1.f / 512.f) + 1e-5f);
    float4 gc = *(const float4*)(g2 + base), gd = *(const float4*)(g2 + base + 4);
    float4 bc = *(const float4*)(b2 + base), bd = *(const float4*)(b2 + base + 4);
    float g2v[8] = {gc.x, gc.y, gc.z, gc.w, gd.x, gd.y, gd.z, gd.w};
    float b2v[8] = {bc.x, bc.y, bc.z, bc.w, bd.x, bd.y, bd.z, bd.w};
    float r[8];
    #pragma unroll
    for (int jj = 0; jj < 8; jj++) r[jj] = (tvec[jj] - m2) * inv2 * g2v[jj] + b2v[jj];
    float* pf = yf + row * 512 + base;
    *(float4*)pf = (float4){r[0], r[1], r[2], r[3]};
    *(float4*)(pf + 4) = (float4){r[4], r[5], r[6], r[7]};
    bf16x8 ov;
    #pragma unroll
    for (int jj = 0; jj < 8; jj++) ov[jj] = (short)f2bf(r[jj]);
    *(bf16x8*)(yb + row * 512 + base) = ov;
}

// =================== LN(a+b): f32 out + bf16 out ===================
__global__ __launch_bounds__(256)
void ln_add2(const float* __restrict__ a, const float* __restrict__ b2,
             const float* __restrict__ g, const float* __restrict__ be,
             float* __restrict__ o, unsigned short* __restrict__ ob)
{
    const int wv = threadIdx.x >> 6, lane = threadIdx.x & 63;
    const long row = (long)blockIdx.x * 4 + wv;
    const int base = lane * 8;
    const float* pa = a + row * 512 + base;
    const float* pb = b2 + row * 512 + base;
    float v[8];
    {
        float4 x0 = *(const float4*)pa, x1 = *(const float4*)(pa + 4);
        float4 y0 = *(const float4*)pb, y1 = *(const float4*)(pb + 4);
        v[0] = x0.x + y0.x; v[1] = x0.y + y0.y; v[2] = x0.z + y0.z; v[3] = x0.w + y0.w;
        v[4] = x1.x + y1.x; v[5] = x1.y + y1.y; v[6] = x1.z + y1.z; v[7] = x1.w + y1.w;
    }
    float s = 0.f;
    #pragma unroll
    for (int jj = 0; jj < 8; jj++) s += v[jj];
    #pragma unroll
    for (int off = 32; off; off >>= 1) s += __shfl_xor(s, off);
    float mean = s * (1.f / 512.f);
    float vs = 0.f;
    #pragma unroll
    for (int jj = 0; jj < 8; jj++) { float d = v[jj] - mean; vs += d * d; }
    #pragma unroll
    for (int off = 32; off; off >>= 1) vs += __shfl_xor(vs, off);
    float inv = rsqrtf(vs * (1.f / 512.f) + 1e-5f);
    float4 g0 = *(const float4*)(g + base), g1 = *(const float4*)(g + base + 4);
    float4 e0 = *(const float4*)(be + base), e1 = *(const float4*)(be + base + 4);
    float gg[8] = {g0.x, g0.y, g0.z, g0.w, g1.x, g1.y, g1.z, g1.w};
    float ee[8] = {e0.x, e0.y, e0.z, e0.w, e1.x, e1.y, e1.z, e1.w};
    float r[8];
    #pragma unroll
    for (int jj = 0; jj < 8; jj++) r[jj] = (v[jj] - mean) * inv * gg[jj] + ee[jj];
    float* po = o + row * 512 + base;
    *(float4*)po = (float4){r[0], r[1], r[2], r[3]};
    *(float4*)(po + 4) = (float4){r[4], r[5], r[6], r[7]};
    bf16x8 ov;
    #pragma unroll
    for (int jj = 0; jj < 8; jj++) ov[jj] = (short)f2bf(r[jj]);
    *(bf16x8*)(ob + row * 512 + base) = ov;
}

// =================== seasonal combine ===================
__global__ __launch_bounds__(256)
void combine2(const float* __restrict__ tr, const float* __restrict__ rs,
              const float* __restrict__ se, const float* __restrict__ comb,
              float* __restrict__ xo, unsigned short* __restrict__ xb)
{
    float c[5]; float m = -1e30f;
    #pragma unroll
    for (int k = 0; k < 5; k++) { c[k] = comb[k]; m = fmaxf(m, c[k]); }
    float s = 0.f;
    #pragma unroll
    for (int k = 0; k < 5; k++) { c[k] = __expf(c[k] - m); s += c[k]; }
    float inv = 1.f / s;
    long i4 = ((long)blockIdx.x * 256 + threadIdx.x) * 4;
    float4 t = *(const float4*)(tr + i4);
    float4 r = *(const float4*)(rs + i4);
    float4 s0 = *(const float4*)(se + i4);
    float4 s1 = *(const float4*)(se + 1048576 + i4);
    float4 s2 = *(const float4*)(se + 2097152 + i4);
    float o[4];
    o[0] = inv * (c[0] * t.x + c[4] * r.x + c[1] * s0.x + c[2] * s1.x + c[3] * s2.x);
    o[1] = inv * (c[0] * t.y + c[4] * r.y + c[1] * s0.y + c[2] * s1.y + c[3] * s2.y);
    o[2] = inv * (c[0] * t.z + c[4] * r.z + c[1] * s0.z + c[2] * s1.z + c[3] * s2.z);
    o[3] = inv * (c[0] * t.w + c[4] * r.w + c[1] * s0.w + c[2] * s1.w + c[3] * s2.w);
    *(float4*)(xo + i4) = (float4){o[0], o[1], o[2], o[3]};
    bf16x4 ov = {(short)f2bf(o[0]), (short)f2bf(o[1]), (short)f2bf(o[2]), (short)f2bf(o[3])};
    *(bf16x4*)(xb + i4) = ov;
}

// ============================ host ============================
#define G3(BM,BN,OBF,BIAS,GACT,RELB,SPART, A,B,C,bias_,rel_, M,N,NKT,SKN, lda,ldb,ldc, alpha, mA,a1,a2, mB,b1,b2, mC,c1,c2, bstr, pstr, Zg) \
    gemm3<BM,BN,OBF,BIAS,GACT,RELB,SPART><<<dim3((M)/(BM), ((N)+(BN)-1)/(BN), (Zg)), dim3(256), 0, stream>>>( \
        (A),(B),(C),(bias_),(rel_),(M),(N),(NKT),(SKN),(lda),(ldb),(ldc),(alpha), \
        (mA),(long)(a1),(long)(a2),(mB),(long)(b1),(long)(b2),(mC),(long)(c1),(long)(c2),(bstr),(long)(pstr))

extern "C" void kernel_launch(void* const* d_in, const int* in_sizes, int n_in,
                              void* d_out, int out_size, void* d_ws, size_t ws_size,
                              hipStream_t stream)
{
    (void)in_sizes; (void)n_in; (void)out_size; (void)ws_size;
    const float* x    = (const float*)d_in[0];
    const float* t1w  = (const float*)d_in[1];
    const float* t1b  = (const float*)d_in[2];
    const float* t2w  = (const float*)d_in[3];
    const float* t2b  = (const float*)d_in[4];
    const float* s1w  = (const float*)d_in[5];
    const float* s1b  = (const float*)d_in[6];
    const float* s2w  = (const float*)d_in[7];
    const float* s2b  = (const float*)d_in[8];
    const float* r1w  = (const float*)d_in[9];
    const float* r1b  = (const float*)d_in[10];
    const float* r2w  = (const float*)d_in[11];
    const float* r2b  = (const float*)d_in[12];
    const float* comb = (const float*)d_in[13];
    const float* wq   = (const float*)d_in[14];
    const float* wk   = (const float*)d_in[15];
    const float* wvv  = (const float*)d_in[16];
    const float* wow  = (const float*)d_in[17];
    const float* wob  = (const float*)d_in[18];
    const float* relk = (const float*)d_in[19];
    const float* relv = (const float*)d_in[20];
    const float* lag  = (const float*)d_in[21];
    const float* labi = (const float*)d_in[22];
    const float* f1w  = (const float*)d_in[23];
    const float* f1b  = (const float*)d_in[24];
    const float* f2w  = (const float*)d_in[25];
    const float* f2b  = (const float*)d_in[26];
    const float* n1g  = (const float*)d_in[27];
    const float* n1b  = (const float*)d_in[28];
    const float* n2g  = (const float*)d_in[29];
    const float* n2b  = (const float*)d_in[30];

    char* ws = (char*)d_ws;
    #define OFFK(kb) (ws + (size_t)(kb) * 1024)
    float* X    = (float*)OFFK(0);          // 4MB [2048][512]
    float* T1   = (float*)OFFK(4096);       // 4MB
    float* T3   = (float*)OFFK(8192);       // 4MB
    float* PART = (float*)OFFK(12288);      // 16MB [4][2048][512] f32 partials
    float* SEAS = (float*)OFFK(12288);      // alias: prologue 12MB
    float* T2   = (float*)OFFK(24576);      // alias (prologue only)
    unsigned short* Xb   = (unsigned short*)OFFK(45056);  // 2MB
    unsigned short* Xb0  = (unsigned short*)OFFK(47104);  // 2MB
    unsigned short* QKVb = (unsigned short*)OFFK(49152);  // 6MB [2048][1536]
    unsigned short* VT   = (unsigned short*)OFFK(55296);  // 2MB [32][64][512]
    unsigned short* CTXb = (unsigned short*)OFFK(57344);  // 2MB
    unsigned short* T3b  = (unsigned short*)OFFK(59392);  // 2MB
    unsigned short* FFb  = (unsigned short*)OFFK(61440);  // 8MB [2048][2048]
    unsigned short* QR   = (unsigned short*)OFFK(86016);  // 32.8MB [2048][8][1025]
    unsigned short* SHb  = (unsigned short*)OFFK(86016);  // alias (prologue): [3][2048][256]
    unsigned short* qkvT = (unsigned short*)OFFK(119808); // 9MB [6][1536][512]
    unsigned short* woT  = (unsigned short*)OFFK(129024); // 3MB
    unsigned short* f1wT = (unsigned short*)OFFK(132096); // 12MB
    unsigned short* f2wT = (unsigned short*)OFFK(144384); // 12MB
    unsigned short* relkb= (unsigned short*)OFFK(156672); // [6][1088][64]
    unsigned short* rvT  = (unsigned short*)OFFK(157488); // [6][64][1056]
    unsigned short* t1wT = (unsigned short*)OFFK(158280);
    unsigned short* t2wT = (unsigned short*)OFFK(158792);
    unsigned short* r1wT = (unsigned short*)OFFK(159304);
    unsigned short* r2wT = (unsigned short*)OFFK(159560);
    unsigned short* s1wT = (unsigned short*)OFFK(159816);
    unsigned short* s2wT = (unsigned short*)OFFK(160584);

    // ---------------- prep: casts + transposes ----------------
    castpad_k<<<dim3(1024, 1, 1), 256, 0, stream>>>(x, Xb0, 2048, 512, 1048576, 1048576, 1048576);
    trcast_k<<<dim3(16, 16, 1), 256, 0, stream>>>(t1w, t1wT, 512, 512, 512, 262144, 262144);
    trcast_k<<<dim3(16, 16, 1), 256, 0, stream>>>(t2w, t2wT, 512, 512, 512, 262144, 262144);
    trcast_k<<<dim3(8, 16, 1), 256, 0, stream>>>(r1w, r1wT, 512, 256, 512, 131072, 131072);
    trcast_k<<<dim3(16, 8, 1), 256, 0, stream>>>(r2w, r2wT, 256, 512, 256, 131072, 131072);
    trcast_k<<<dim3(8, 16, 3), 256, 0, stream>>>(s1w, s1wT, 512, 256, 512, 131072, 131072);
    trcast_k<<<dim3(16, 8, 3), 256, 0, stream>>>(s2w, s2wT, 256, 512, 256, 131072, 131072);
    trcast_k<<<dim3(16, 16, 6), 256, 0, stream>>>(wq,  qkvT,          512, 512, 512, 262144, 786432);
    trcast_k<<<dim3(16, 16, 6), 256, 0, stream>>>(wk,  qkvT + 262144, 512, 512, 512, 262144, 786432);
    trcast_k<<<dim3(16, 16, 6), 256, 0, stream>>>(wvv, qkvT + 524288, 512, 512, 512, 262144, 786432);
    trcast_k<<<dim3(16, 16, 6), 256, 0, stream>>>(wow, woT, 512, 512, 512, 262144, 262144);
    trcast_k<<<dim3(64, 16, 6), 256, 0, stream>>>(f1w, f1wT, 512, 2048, 512, 1048576, 1048576);
    trcast_k<<<dim3(16, 64, 6), 256, 0, stream>>>(f2w, f2wT, 2048, 512, 2048, 1048576, 1048576);
    trcast_k<<<dim3(2, 33, 6), 256, 0, stream>>>(relv, rvT, 1025, 64, 1056, 65600, 67584);
    castpad_k<<<dim3(272, 1, 6), 256, 0, stream>>>(relk, relkb, 1025, 64, 65600, 69632, 69632);

    // ---------------- seasonal decomposition ----------------
    G3(64,64,true,true,true,false,false,   Xb0, t1wT, T3b,  t1b, nullptr, 2048,512,16,1, 512,512,512, 1.f, 1,0,0, 1,0,0, 1,0,0, 0,0, 1);
    G3(64,64,false,true,false,false,false, T3b, t2wT, T1,   t2b, nullptr, 2048,512,16,1, 512,512,512, 1.f, 1,0,0, 1,0,0, 1,0,0, 0,0, 1);
    G3(64,64,true,true,true,false,false,   Xb0, r1wT, CTXb, r1b, nullptr, 2048,256,16,1, 512,512,256, 1.f, 1,0,0, 1,0,0, 1,0,0, 0,0, 1);
    G3(64,64,false,true,false,false,false, CTXb,r2wT, T2,   r2b, nullptr, 2048,512,8,1,  256,256,512, 1.f, 1,0,0, 1,0,0, 1,0,0, 0,0, 1);
    G3(64,64,true,true,true,false,false,   Xb0, s1wT, SHb,  s1b, nullptr, 2048,256,16,1, 512,512,256, 1.f, 1,0,0, 3,131072,0, 3,524288,0, 256,0, 3);
    G3(64,64,false,true,false,false,false, SHb, s2wT, SEAS, s2b, nullptr, 2048,512,8,1,  256,256,512, 1.f, 3,524288,0, 3,131072,0, 3,1048576,0, 512,0, 3);
    combine2<<<dim3(1024), 256, 0, stream>>>(T1, T2, SEAS, comb, X, Xb);

    // ---------------- transformer layers ----------------
    for (int l = 0; l < NL; ++l) {
        const unsigned short* qkvTl = qkvT + (long)l * 786432;
        const unsigned short* woTl  = woT + (long)l * 262144;
        const unsigned short* f1Tl  = f1wT + (long)l * 1048576;
        const unsigned short* f2Tl  = f2wT + (long)l * 1048576;
        const unsigned short* rkl   = relkb + (long)l * 69632;
        const unsigned short* rvl   = rvT + (long)l * 67584;

        // QKV (merged)
        G3(64,64,true,false,false,false,false, Xb, qkvTl, QKVb, nullptr, nullptr, 2048,1536,16,1, 512,512,1536, 1.f,
           1,0,0, 1,0,0, 1,0,0, 0,0, 1);
        transp_v<<<dim3(16, 16, 4), 256, 0, stream>>>(QKVb + 1024, VT, 1536);
        // qrel[bi][h][r] = Q . rel_k_r  (batched over h)
        G3(64,64,true,false,false,false,false, QKVb, rkl, QR, nullptr, nullptr, 2048,1025,2,1, 1536,64,8200, 1.f,
           8,64,0, 1,0,0, 8,1025,0, 0,0, 8);
        // fused flash attention (scores + bias + softmax + PV + rel-v)
        fused_attn<<<dim3(8, 32, 1), 256, 0, stream>>>(QKVb, VT, QR, rvl, CTXb);
        // out = ctx @ wo + b
        G3(64,64,false,true,false,false,false, CTXb, woTl, T1, wob + l * 512, nullptr, 2048,512,16,1, 512,512,512, 1.f,
           1,0,0, 1,0,0, 1,0,0, 0,0, 1);
        // y1 = LN(x + LN(out + x))
        ln2x_k<<<dim3(512), 256, 0, stream>>>(T1, X, lag + l * 512, labi + l * 512,
                                              n1g + l * 512, n1b + l * 512, T3, T3b);
        // FF
        G3(64,64,true,true,true,false,false, T3b, f1Tl, FFb, f1b + l * 2048, nullptr, 2048,2048,16,1, 512,512,2048, 1.f,
           1,0,0, 1,0,0, 1,0,0, 0,0, 1);
        G3(64,64,false,false,false,false,true, FFb, f2Tl, PART, nullptr, nullptr, 2048,512,16,4, 2048,2048,512, 1.f,
           1,0,0, 1,0,0, 1,0,0, 0,1048576, 4);
        reduce_k<4,true,true,false><<<dim3(1024), 256, 0, stream>>>(PART, f2b + l * 512, T1, nullptr, 511, 1048576);
        // y = LN(y1 + ff)
        float* outp = (l == NL - 1) ? (float*)d_out : X;
        ln_add2<<<dim3(512), 256, 0, stream>>>(T3, T1, n2g + l * 512, n2b + l * 512, outp, Xb);
    }
}

// Round 6
// 608.076 us; speedup vs baseline: 4.2198x; 1.2162x over previous
//
#include <hip/hip_runtime.h>
#include <hip/hip_bf16.h>

typedef __attribute__((ext_vector_type(4))) float f32x4;
typedef __attribute__((ext_vector_type(8))) short bf16x8;
typedef __attribute__((ext_vector_type(4))) short bf16x4;

#define NL 6

static __device__ __forceinline__ unsigned short f2bf(float f) {
    __hip_bfloat16 h = __float2bfloat16(f);
    return *reinterpret_cast<unsigned short*>(&h);
}
static __device__ __forceinline__ float bf2f(unsigned short u) {
    union { unsigned int u32; float f; } c; c.u32 = ((unsigned int)u) << 16; return c.f;
}
static __device__ __forceinline__ float gelu_exact(float v) {
    return 0.5f * v * (1.0f + erff(v * 0.70710678118654752f));
}
static __device__ __forceinline__ void gload_lds16(const void* g, void* l) {
    __builtin_amdgcn_global_load_lds((const __attribute__((address_space(1))) void*)g,
                                     (__attribute__((address_space(3))) void*)l, 16, 0, 0);
}
static __device__ __forceinline__ f32x4 MF(bf16x8 a, bf16x8 b, f32x4 c) {
    return __builtin_amdgcn_mfma_f32_16x16x32_bf16(a, b, c, 0, 0, 0);
}

// ============================ GEMM ============================
// C[M,N] = alpha * A[M,K] @ B^T[N,K] (+bias)(gelu), A/B bf16.
// SPART: write f32 partial to C + sk*pStride. DUAL: write f32 C and bf16 C2.
template<int BM, int BN, bool OBF, bool BIAS, bool GACT, bool SPART, bool DUAL>
__global__ __launch_bounds__(256)
void gemm3(const unsigned short* __restrict__ A, const unsigned short* __restrict__ B,
           void* __restrict__ C, unsigned short* __restrict__ C2,
           const float* __restrict__ bias,
           int M, int N, int nkt, int skN, int lda, int ldb, int ldc, float alpha,
           int modA, long sA1, long sA2, int modB, long sB1, long sB2,
           int modC, long sC1, long sC2, int biasStride, long pStride)
{
    constexpr int MI = BM / 32, NI = BN / 32;
    constexpr int ACH = BM / 16, NCH = (BM + BN) / 16;
    __shared__ __attribute__((aligned(16))) unsigned short Ls[(BM + BN) * 32];

    const int bz = blockIdx.z;
    const int sk = SPART ? (bz % skN) : 0;
    const int z  = SPART ? (bz / skN) : bz;
    const unsigned short* Ab = A + (long)(z % modA) * sA1 + (long)(z / modA) * sA2;
    const unsigned short* Bb = B + (long)(z % modB) * sB1 + (long)(z / modB) * sB2;
    const long offC = (long)(z % modC) * sC1 + (long)(z / modC) * sC2;

    const int bm0 = blockIdx.x * BM, bn0 = blockIdx.y * BN;
    const int t = threadIdx.x, lane = t & 63, w = t >> 6;
    const int wm = (w >> 1) * (BM / 2), wn = (w & 1) * (BN / 2);
    const int crow = lane >> 2, cs = lane & 3;
    const int fr = lane & 15, kq = lane >> 4;
    const int kBase = sk * nkt * 32;

    f32x4 acc[MI][NI];
    #pragma unroll
    for (int a = 0; a < MI; a++)
        #pragma unroll
        for (int b = 0; b < NI; b++) acc[a][b] = (f32x4){0.f, 0.f, 0.f, 0.f};

    for (int kt = 0; kt < nkt; ++kt) {
        const int k0 = kBase + (kt << 5);
        #pragma unroll
        for (int c0 = 0; c0 < NCH; c0 += 4) {
            int c = c0 + w;
            if (c < NCH) {
                const unsigned short* gp;
                if (c < ACH) {
                    int rit = c * 16 + crow;
                    int ks = cs ^ (rit & 3);
                    gp = Ab + (long)(bm0 + rit) * lda + k0 + ks * 8;
                } else {
                    int rit = (c - ACH) * 16 + crow;
                    int ks = cs ^ (rit & 3);
                    gp = Bb + (long)(bn0 + rit) * ldb + k0 + ks * 8;
                }
                gload_lds16(gp, &Ls[c * 512]);
            }
        }
        __syncthreads();
        bf16x8 af[MI], bfr[NI];
        #pragma unroll
        for (int mi = 0; mi < MI; mi++) {
            int R = wm + mi * 16 + fr;
            af[mi] = *(const bf16x8*)&Ls[R * 32 + ((kq ^ (R & 3)) << 3)];
        }
        #pragma unroll
        for (int ni = 0; ni < NI; ni++) {
            int Rb = wn + ni * 16 + fr;
            bfr[ni] = *(const bf16x8*)&Ls[BM * 32 + Rb * 32 + ((kq ^ (Rb & 3)) << 3)];
        }
        #pragma unroll
        for (int mi = 0; mi < MI; mi++)
            #pragma unroll
            for (int ni = 0; ni < NI; ni++)
                acc[mi][ni] = MF(af[mi], bfr[ni], acc[mi][ni]);
        __syncthreads();
    }

    const int q4 = (lane >> 4) << 2;
    if (SPART) {
        float* P = (float*)C + sk * pStride + offC;
        #pragma unroll
        for (int mi = 0; mi < MI; mi++)
            #pragma unroll
            for (int ni = 0; ni < NI; ni++)
                #pragma unroll
                for (int j = 0; j < 4; j++) {
                    int gr = bm0 + wm + mi * 16 + q4 + j;
                    int gc = bn0 + wn + ni * 16 + fr;
                    if (gc < N) P[(long)gr * ldc + gc] = acc[mi][ni][j] * alpha;
                }
    } else {
        float* Cf = (float*)C + offC;
        unsigned short* Ch = (unsigned short*)C + offC;
        unsigned short* C2h = DUAL ? (C2 + offC) : nullptr;
        const float* bp = BIAS ? (bias + (long)z * biasStride) : nullptr;
        #pragma unroll
        for (int mi = 0; mi < MI; mi++)
            #pragma unroll
            for (int ni = 0; ni < NI; ni++)
                #pragma unroll
                for (int j = 0; j < 4; j++) {
                    int gr = bm0 + wm + mi * 16 + q4 + j;
                    int gc = bn0 + wn + ni * 16 + fr;
                    if (gc < N) {
                        float v = acc[mi][ni][j] * alpha;
                        if (BIAS) v += bp[gc];
                        if (GACT) v = gelu_exact(v);
                        if (OBF) Ch[(long)gr * ldc + gc] = f2bf(v);
                        else     Cf[(long)gr * ldc + gc] = v;
                        if (DUAL) C2h[(long)gr * ldc + gc] = f2bf(v);
                    }
                }
    }
}

// ==================== fused flash attention v2 ====================
// In-kernel rel-k bias via band MFMA; double-buffered staging.
// grid (8 i-tiles, 32 bh), 256 threads. LDS 128KB.
__global__ __launch_bounds__(256)
void fused_attn2(const unsigned short* __restrict__ qkv,
                 const unsigned short* __restrict__ vt,
                 const unsigned short* __restrict__ rk,
                 const unsigned short* __restrict__ rvt,
                 unsigned short* __restrict__ ctx)
{
    // shorts: Q 0..4096 | STG[2] @4096+s*24576 {K 0,V 4096,RV 8192,RK 16384} | P 53248 | G/A 57344
    __shared__ __attribute__((aligned(16))) unsigned short L[65536];
    const int bh = blockIdx.y, b = bh >> 3, h = bh & 7;
    const int i0 = blockIdx.x * 64;
    const int t = threadIdx.x, lane = t & 63, wv = t >> 6;
    const int crow = lane >> 2, cs = lane & 3;
    const int fr = lane & 15, kq = lane >> 4;
    const int q4 = kq << 2;
    const int iiw = wv * 16;
    const int PB = 53248, GA = 57344;

    const unsigned short* Qg = qkv + ((long)(b * 512 + i0)) * 1536 + h * 64;
    const unsigned short* Kg = qkv + ((long)(b * 512)) * 1536 + 512 + h * 64;
    const unsigned short* Vg = vt + ((long)bh * 64) * 512;

    auto stage = [&](int jt, int sbuf) {
        const int j0 = jt * 64, rbase = j0 - i0 + 448;
        const int SB = 4096 + sbuf * 24576;
        #pragma unroll
        for (int k = 0; k < 12; k++) {
            int c = wv + k * 4;
            const unsigned short* gp; int dst;
            if (c < 8) {
                int kt = c >> 2, row = (c & 3) * 16 + crow, ks = cs ^ (row & 3);
                gp = Kg + (long)(j0 + row) * 1536 + kt * 32 + ks * 8;
                dst = SB + c * 512;
            } else if (c < 16) {
                int cc = c - 8;
                int kt = cc >> 2, row = (cc & 3) * 16 + crow, ks = cs ^ (row & 3);
                gp = Vg + (long)row * 512 + j0 + kt * 32 + ks * 8;
                dst = SB + 4096 + cc * 512;
            } else if (c < 32) {
                int cc = c - 16;
                int kt = cc >> 2, row = (cc & 3) * 16 + crow, ks = cs ^ (row & 3);
                gp = rvt + (long)row * 1056 + rbase + kt * 32 + ks * 8;
                dst = SB + 8192 + cc * 512;
            } else {
                int cc = c - 32;
                int kt = cc >> 3, row = (cc & 7) * 16 + crow, ks = cs ^ (row & 3);
                gp = rk + (long)(rbase + row) * 64 + kt * 32 + ks * 8;
                dst = SB + 16384 + cc * 512;
            }
            gload_lds16(gp, &L[dst]);
        }
    };

    // prologue: Q + stage(0)
    #pragma unroll
    for (int k = 0; k < 2; k++) {
        int c = wv + k * 4;
        int kt = c >> 2, row = (c & 3) * 16 + crow, ks = cs ^ (row & 3);
        gload_lds16(Qg + (long)row * 1536 + kt * 32 + ks * 8, &L[c * 512]);
    }
    stage(0, 0);
    __syncthreads();
    bf16x8 qf[2];
    {
        int r = iiw + fr;
        qf[0] = *(const bf16x8*)&L[r * 32 + ((kq ^ (r & 3)) << 3)];
        qf[1] = *(const bf16x8*)&L[2048 + r * 32 + ((kq ^ (r & 3)) << 3)];
    }

    f32x4 ctxa[4];
    #pragma unroll
    for (int ni = 0; ni < 4; ni++) ctxa[ni] = (f32x4){0.f, 0.f, 0.f, 0.f};
    float m_[4] = {-1e30f, -1e30f, -1e30f, -1e30f};
    float l_[4] = {0.f, 0.f, 0.f, 0.f};

    for (int jt = 0; jt < 8; ++jt) {
        const int sb = jt & 1;
        const int SB = 4096 + sb * 24576;
        if (jt < 7) stage(jt + 1, sb ^ 1);
        // ---- G = Q @ RK_band^T  (bias band, w in [0,128)) ----
        f32x4 gacc[8];
        #pragma unroll
        for (int wb = 0; wb < 8; wb++) {
            int Rb = wb * 16 + fr;
            bf16x8 rk0 = *(const bf16x8*)&L[SB + 16384 + Rb * 32 + ((kq ^ (Rb & 3)) << 3)];
            bf16x8 rk1 = *(const bf16x8*)&L[SB + 20480 + Rb * 32 + ((kq ^ (Rb & 3)) << 3)];
            f32x4 g = (f32x4){0.f, 0.f, 0.f, 0.f};
            g = MF(qf[0], rk0, g);
            gacc[wb] = MF(qf[1], rk1, g);
        }
        #pragma unroll
        for (int wb = 0; wb < 8; wb++)
            #pragma unroll
            for (int j = 0; j < 4; j++) {
                int il = iiw + q4 + j, ww = wb * 16 + fr;
                L[GA + il * 128 + (((ww >> 3) ^ (il & 7)) << 3) + (ww & 7)] = f2bf(gacc[wb][j]);
            }
        // ---- S = Q @ K^T ----
        f32x4 s[4];
        #pragma unroll
        for (int ni = 0; ni < 4; ni++) {
            int rB = ni * 16 + fr;
            bf16x8 b0 = *(const bf16x8*)&L[SB + rB * 32 + ((kq ^ (rB & 3)) << 3)];
            bf16x8 b1 = *(const bf16x8*)&L[SB + 2048 + rB * 32 + ((kq ^ (rB & 3)) << 3)];
            f32x4 a0 = (f32x4){0.f, 0.f, 0.f, 0.f};
            a0 = MF(qf[0], b0, a0);
            s[ni] = MF(qf[1], b1, a0);
        }
        // ---- scale + rel-k bias gather (wave-local G; ww = jj - il + 64) ----
        #pragma unroll
        for (int ni = 0; ni < 4; ni++)
            #pragma unroll
            for (int j = 0; j < 4; j++) {
                int il = iiw + q4 + j;
                int ww = ni * 16 + fr - il + 64;   // FIXED: include iiw in il
                s[ni][j] = s[ni][j] * 0.125f
                         + bf2f(L[GA + il * 128 + (((ww >> 3) ^ (il & 7)) << 3) + (ww & 7)]);
            }
        // ---- online softmax ----
        float mx[4];
        #pragma unroll
        for (int j = 0; j < 4; j++) {
            mx[j] = fmaxf(fmaxf(s[0][j], s[1][j]), fmaxf(s[2][j], s[3][j]));
            #pragma unroll
            for (int msk = 1; msk < 16; msk <<= 1) mx[j] = fmaxf(mx[j], __shfl_xor(mx[j], msk));
        }
        float scl[4];
        #pragma unroll
        for (int j = 0; j < 4; j++) {
            float mn = fmaxf(m_[j], mx[j]);
            scl[j] = __expf(m_[j] - mn);
            m_[j] = mn;
        }
        float rs[4] = {0.f, 0.f, 0.f, 0.f};
        #pragma unroll
        for (int ni = 0; ni < 4; ni++)
            #pragma unroll
            for (int j = 0; j < 4; j++) {
                float p = __expf(s[ni][j] - m_[j]);
                s[ni][j] = p;
                rs[j] += p;
            }
        #pragma unroll
        for (int j = 0; j < 4; j++) {
            #pragma unroll
            for (int msk = 1; msk < 16; msk <<= 1) rs[j] += __shfl_xor(rs[j], msk);
            l_[j] = l_[j] * scl[j] + rs[j];
        }
        #pragma unroll
        for (int ni = 0; ni < 4; ni++)
            #pragma unroll
            for (int j = 0; j < 4; j++) ctxa[ni][j] *= scl[j];
        // ---- write P and shifted A (A overwrites G; all 128 slots covered) ----
        #pragma unroll
        for (int ni = 0; ni < 4; ni++)
            #pragma unroll
            for (int j = 0; j < 4; j++) {
                int il = iiw + q4 + j;
                int jj = ni * 16 + fr;
                unsigned short pb = f2bf(s[ni][j]);
                L[PB + il * 64 + (((jj >> 3) ^ (il & 7)) << 3) + (jj & 7)] = pb;
                int wI = jj - il + 64;           // in [1,127]
                L[GA + il * 128 + (((wI >> 3) ^ (il & 7)) << 3) + (wI & 7)] = pb;
                int wz = (wI + 64) & 127;
                L[GA + il * 128 + (((wz >> 3) ^ (il & 7)) << 3) + (wz & 7)] = 0;
            }
        // ---- PV + A @ relv^T ----
        const int r = iiw + fr;
        bf16x8 pa0 = *(const bf16x8*)&L[PB + r * 64 + ((kq ^ (r & 7)) << 3)];
        bf16x8 pa1 = *(const bf16x8*)&L[PB + r * 64 + (((4 + kq) ^ (r & 7)) << 3)];
        #pragma unroll
        for (int ni = 0; ni < 4; ni++) {
            int rB = ni * 16 + fr;
            bf16x8 vb0 = *(const bf16x8*)&L[SB + 4096 + rB * 32 + ((kq ^ (rB & 3)) << 3)];
            bf16x8 vb1 = *(const bf16x8*)&L[SB + 6144 + rB * 32 + ((kq ^ (rB & 3)) << 3)];
            ctxa[ni] = MF(pa0, vb0, ctxa[ni]);
            ctxa[ni] = MF(pa1, vb1, ctxa[ni]);
        }
        #pragma unroll
        for (int kt2 = 0; kt2 < 4; kt2++) {
            bf16x8 aa = *(const bf16x8*)&L[GA + r * 128 + (((kt2 * 4 + kq) ^ (r & 7)) << 3)];
            #pragma unroll
            for (int ni = 0; ni < 4; ni++) {
                int rB = ni * 16 + fr;
                bf16x8 rb = *(const bf16x8*)&L[SB + 8192 + kt2 * 2048 + rB * 32 + ((kq ^ (rB & 3)) << 3)];
                ctxa[ni] = MF(aa, rb, ctxa[ni]);
            }
        }
        __syncthreads();   // drains next-tile staging; protects double buffer
    }
    // epilogue
    #pragma unroll
    for (int j = 0; j < 4; j++) {
        float inv = 1.f / l_[j];
        int il = iiw + q4 + j;
        unsigned short* op = ctx + ((long)(b * 512 + i0 + il)) * 512 + h * 64;
        #pragma unroll
        for (int ni = 0; ni < 4; ni++)
            op[ni * 16 + fr] = f2bf(ctxa[ni][j] * inv);
    }
}

// =================== transpose-cast f32 -> bf16^T (opt scale) ===================
__global__ __launch_bounds__(256)
void trcast_k(const float* __restrict__ in, unsigned short* __restrict__ out,
              int R, int C, int ldo, long inStride, long outStride,
              const float* __restrict__ scp, int sczs)
{
    __shared__ unsigned short tile[32][33];
    const int z = blockIdx.z;
    const float* ip = in + (long)z * inStride;
    unsigned short* op = out + (long)z * outStride;
    const float sc = scp ? scp[z * sczs] : 1.0f;
    const int c0 = blockIdx.x * 32, r0 = blockIdx.y * 32;
    const int tx = threadIdx.x & 31, ty = threadIdx.x >> 5;
    #pragma unroll
    for (int q = 0; q < 4; q++) {
        int r = r0 + ty + q * 8;
        float v = (r < R) ? ip[(long)r * C + c0 + tx] * sc : 0.f;
        tile[ty + q * 8][tx] = f2bf(v);
    }
    __syncthreads();
    #pragma unroll
    for (int q = 0; q < 4; q++) {
        int c = c0 + ty + q * 8;
        op[(long)c * ldo + r0 + tx] = tile[tx][ty + q * 8];
    }
}

// =================== cast (+row-pad) f32 -> bf16 ===================
__global__ __launch_bounds__(256)
void castpad_k(const float* __restrict__ in, unsigned short* __restrict__ out,
               int R, int C, long inStride, long outStride, long nPerZ)
{
    const int z = blockIdx.z;
    for (long idx = (long)blockIdx.x * 256 + threadIdx.x; idx < nPerZ;
         idx += (long)gridDim.x * 256) {
        int r = (int)(idx / C);
        float v = (r < R) ? in[(long)z * inStride + idx] : 0.f;
        out[(long)z * outStride + idx] = f2bf(v);
    }
}

// =================== V transpose ===================
__global__ __launch_bounds__(256)
void transp_v(const unsigned short* __restrict__ v, unsigned short* __restrict__ vt, int ldv)
{
    __shared__ unsigned short tile[32][33];
    const int b = blockIdx.z;
    const int j0 = blockIdx.x * 32, c0 = blockIdx.y * 32;
    const int tx = threadIdx.x & 31, ty = threadIdx.x >> 5;
    #pragma unroll
    for (int q = 0; q < 4; q++)
        tile[ty + q * 8][tx] = v[(long)(b * 512 + j0 + ty + q * 8) * ldv + c0 + tx];
    __syncthreads();
    #pragma unroll
    for (int q = 0; q < 4; q++) {
        int c = c0 + ty + q * 8;
        int h = c >> 6, d = c & 63;
        vt[((long)(b * 8 + h) * 64 + d) * 512 + j0 + tx] = tile[tx][ty + q * 8];
    }
}

// =================== ln2x: y = LN2(x + LN1(p0+p1+wb + x)) ===================
__global__ __launch_bounds__(256)
void ln2x_k(const float* __restrict__ p0, const float* __restrict__ p1,
            const float* __restrict__ wb, const float* __restrict__ x,
            const float* __restrict__ g1, const float* __restrict__ b1,
            const float* __restrict__ g2, const float* __restrict__ b2,
            float* __restrict__ yf, unsigned short* __restrict__ yb)
{
    const int wv = threadIdx.x >> 6, lane = threadIdx.x & 63;
    const long row = (long)blockIdx.x * 4 + wv;
    const int base = lane * 8;
    const float* pa = p0 + row * 512 + base;
    const float* pbp = p1 + row * 512 + base;
    const float* px = x + row * 512 + base;
    float xv[8], v[8];
    {
        float4 x0 = *(const float4*)px, x1 = *(const float4*)(px + 4);
        float4 a0 = *(const float4*)pa, a1 = *(const float4*)(pa + 4);
        float4 c0 = *(const float4*)pbp, c1 = *(const float4*)(pbp + 4);
        float4 w0 = *(const float4*)(wb + base), w1 = *(const float4*)(wb + base + 4);
        xv[0] = x0.x; xv[1] = x0.y; xv[2] = x0.z; xv[3] = x0.w;
        xv[4] = x1.x; xv[5] = x1.y; xv[6] = x1.z; xv[7] = x1.w;
        v[0] = xv[0] + a0.x + c0.x + w0.x; v[1] = xv[1] + a0.y + c0.y + w0.y;
        v[2] = xv[2] + a0.z + c0.z + w0.z; v[3] = xv[3] + a0.w + c0.w + w0.w;
        v[4] = xv[4] + a1.x + c1.x + w1.x; v[5] = xv[5] + a1.y + c1.y + w1.y;
        v[6] = xv[6] + a1.z + c1.z + w1.z; v[7] = xv[7] + a1.w + c1.w + w1.w;
    }
    float s = 0.f;
    #pragma unroll
    for (int jj = 0; jj < 8; jj++) s += v[jj];
    #pragma unroll
    for (int off = 32; off; off >>= 1) s += __shfl_xor(s, off);
    float mean = s * (1.f / 512.f);
    float vs = 0.f;
    #pragma unroll
    for (int jj = 0; jj < 8; jj++) { float d = v[jj] - mean; vs += d * d; }
    #pragma unroll
    for (int off = 32; off; off >>= 1) vs += __shfl_xor(vs, off);
    float inv = rsqrtf(vs * (1.f / 512.f) + 1e-5f);
    float4 ga = *(const float4*)(g1 + base), gb = *(const float4*)(g1 + base + 4);
    float4 ba = *(const float4*)(b1 + base), bb = *(const float4*)(b1 + base + 4);
    float gg[8] = {ga.x, ga.y, ga.z, ga.w, gb.x, gb.y, gb.z, gb.w};
    float ee[8] = {ba.x, ba.y, ba.z, ba.w, bb.x, bb.y, bb.z, bb.w};
    float tvec[8];
    #pragma unroll
    for (int jj = 0; jj < 8; jj++) tvec[jj] = xv[jj] + (v[jj] - mean) * inv * gg[jj] + ee[jj];
    float s2 = 0.f;
    #pragma unroll
    for (int jj = 0; jj < 8; jj++) s2 += tvec[jj];
    #pragma unroll
    for (int off = 32; off; off >>= 1) s2 += __shfl_xor(s2, off);
    float m2 = s2 * (1.f / 512.f);
    float vs2 = 0.f;
    #pragma unroll
    for (int jj = 0; jj < 8; jj++) { float d = tvec[jj] - m2; vs2 += d * d; }
    #pragma unroll
    for (int off = 32; off; off >>= 1) vs2 += __shfl_xor(vs2, off);
    float inv2 = rsqrtf(vs2 * (1.f / 512.f) + 1e-5f);
    float4 gc = *(const float4*)(g2 + base), gd = *(const float4*)(g2 + base + 4);
    float4 bc = *(const float4*)(b2 + base), bd = *(const float4*)(b2 + base + 4);
    float g2v[8] = {gc.x, gc.y, gc.z, gc.w, gd.x, gd.y, gd.z, gd.w};
    float b2v[8] = {bc.x, bc.y, bc.z, bc.w, bd.x, bd.y, bd.z, bd.w};
    float r[8];
    #pragma unroll
    for (int jj = 0; jj < 8; jj++) r[jj] = (tvec[jj] - m2) * inv2 * g2v[jj] + b2v[jj];
    float* pf = yf + row * 512 + base;
    *(float4*)pf = (float4){r[0], r[1], r[2], r[3]};
    *(float4*)(pf + 4) = (float4){r[4], r[5], r[6], r[7]};
    bf16x8 ov;
    #pragma unroll
    for (int jj = 0; jj < 8; jj++) ov[jj] = (short)f2bf(r[jj]);
    *(bf16x8*)(yb + row * 512 + base) = ov;
}

// =================== lnff: y = LN(y1 + sum4(parts)+bias) ===================
__global__ __launch_bounds__(256)
void lnff_k(const float* __restrict__ y1, const float* __restrict__ parts,
            const float* __restrict__ bias,
            const float* __restrict__ g, const float* __restrict__ be,
            float* __restrict__ o, unsigned short* __restrict__ ob)
{
    const int wv = threadIdx.x >> 6, lane = threadIdx.x & 63;
    const long row = (long)blockIdx.x * 4 + wv;
    const int base = lane * 8;
    const float* pa = y1 + row * 512 + base;
    float v[8];
    {
        float4 x0 = *(const float4*)pa, x1 = *(const float4*)(pa + 4);
        float4 w0 = *(const float4*)(bias + base), w1 = *(const float4*)(bias + base + 4);
        v[0] = x0.x + w0.x; v[1] = x0.y + w0.y; v[2] = x0.z + w0.z; v[3] = x0.w + w0.w;
        v[4] = x1.x + w1.x; v[5] = x1.y + w1.y; v[6] = x1.z + w1.z; v[7] = x1.w + w1.w;
    }
    #pragma unroll
    for (int k = 0; k < 4; k++) {
        const float* pp = parts + (long)k * 1048576 + row * 512 + base;
        float4 a0 = *(const float4*)pp, a1 = *(const float4*)(pp + 4);
        v[0] += a0.x; v[1] += a0.y; v[2] += a0.z; v[3] += a0.w;
        v[4] += a1.x; v[5] += a1.y; v[6] += a1.z; v[7] += a1.w;
    }
    float s = 0.f;
    #pragma unroll
    for (int jj = 0; jj < 8; jj++) s += v[jj];
    #pragma unroll
    for (int off = 32; off; off >>= 1) s += __shfl_xor(s, off);
    float mean = s * (1.f / 512.f);
    float vs = 0.f;
    #pragma unroll
    for (int jj = 0; jj < 8; jj++) { float d = v[jj] - mean; vs += d * d; }
    #pragma unroll
    for (int off = 32; off; off >>= 1) vs += __shfl_xor(vs, off);
    float inv = rsqrtf(vs * (1.f / 512.f) + 1e-5f);
    float4 g0 = *(const float4*)(g + base), g1 = *(const float4*)(g + base + 4);
    float4 e0 = *(const float4*)(be + base), e1 = *(const float4*)(be + base + 4);
    float gg[8] = {g0.x, g0.y, g0.z, g0.w, g1.x, g1.y, g1.z, g1.w};
    float ee[8] = {e0.x, e0.y, e0.z, e0.w, e1.x, e1.y, e1.z, e1.w};
    float r[8];
    #pragma unroll
    for (int jj = 0; jj < 8; jj++) r[jj] = (v[jj] - mean) * inv * gg[jj] + ee[jj];
    float* po = o + row * 512 + base;
    *(float4*)po = (float4){r[0], r[1], r[2], r[3]};
    *(float4*)(po + 4) = (float4){r[4], r[5], r[6], r[7]};
    bf16x8 ov;
    #pragma unroll
    for (int jj = 0; jj < 8; jj++) ov[jj] = (short)f2bf(r[jj]);
    *(bf16x8*)(ob + row * 512 + base) = ov;
}

// =================== seasonal prep ===================
__global__ void softmax5_k(const float* __restrict__ comb, float* __restrict__ c5)
{
    if (threadIdx.x == 0 && blockIdx.x == 0) {
        float c[5]; float m = -1e30f;
        for (int k = 0; k < 5; k++) { c[k] = comb[k]; m = fmaxf(m, c[k]); }
        float s = 0.f;
        for (int k = 0; k < 5; k++) { c[k] = __expf(c[k] - m); s += c[k]; }
        for (int k = 0; k < 5; k++) c5[k] = c[k] / s;
    }
}

__global__ __launch_bounds__(256)
void bias_build_k(const float* __restrict__ t1b, const float* __restrict__ r1b,
                  const float* __restrict__ s1b, const float* __restrict__ t2b,
                  const float* __restrict__ r2b, const float* __restrict__ s2b,
                  const float* __restrict__ c5, float* __restrict__ b1c,
                  float* __restrict__ bc)
{
    int i = threadIdx.x + blockIdx.x * 256;
    if (i < 512) b1c[i] = t1b[i];
    else if (i < 768) b1c[i] = r1b[i - 512];
    else if (i < 1536) b1c[i] = s1b[i - 768];
    else if (i < 2048) {
        int n = i - 1536;
        bc[n] = c5[0] * t2b[n] + c5[4] * r2b[n]
              + c5[1] * s2b[n] + c5[2] * s2b[512 + n] + c5[3] * s2b[1024 + n];
    }
}

// ============================ host ============================
#define G3(BM,BN,OBF,BIAS,GACT,SPART,DUAL, A,B,C,C2,bias_, M,N,NKT,SKN, lda,ldb,ldc, alpha, mA,a1,a2, mB,b1,b2, mC,c1,c2, bstr, pstr, Zg) \
    gemm3<BM,BN,OBF,BIAS,GACT,SPART,DUAL><<<dim3((M)/(BM), ((N)+(BN)-1)/(BN), (Zg)), dim3(256), 0, stream>>>( \
        (A),(B),(C),(C2),(bias_),(M),(N),(NKT),(SKN),(lda),(ldb),(ldc),(alpha), \
        (mA),(long)(a1),(long)(a2),(mB),(long)(b1),(long)(b2),(mC),(long)(c1),(long)(c2),(bstr),(long)(pstr))

extern "C" void kernel_launch(void* const* d_in, const int* in_sizes, int n_in,
                              void* d_out, int out_size, void* d_ws, size_t ws_size,
                              hipStream_t stream)
{
    (void)in_sizes; (void)n_in; (void)out_size; (void)ws_size;
    const float* x    = (const float*)d_in[0];
    const float* t1w  = (const float*)d_in[1];
    const float* t1b  = (const float*)d_in[2];
    const float* t2w  = (const float*)d_in[3];
    const float* t2b  = (const float*)d_in[4];
    const float* s1w  = (const float*)d_in[5];
    const float* s1b  = (const float*)d_in[6];
    const float* s2w  = (const float*)d_in[7];
    const float* s2b  = (const float*)d_in[8];
    const float* r1w  = (const float*)d_in[9];
    const float* r1b  = (const float*)d_in[10];
    const float* r2w  = (const float*)d_in[11];
    const float* r2b  = (const float*)d_in[12];
    const float* comb = (const float*)d_in[13];
    const float* wq   = (const float*)d_in[14];
    const float* wk   = (const float*)d_in[15];
    const float* wvv  = (const float*)d_in[16];
    const float* wow  = (const float*)d_in[17];
    const float* wob  = (const float*)d_in[18];
    const float* relk = (const float*)d_in[19];
    const float* relv = (const float*)d_in[20];
    const float* lag  = (const float*)d_in[21];
    const float* labi = (const float*)d_in[22];
    const float* f1w  = (const float*)d_in[23];
    const float* f1b  = (const float*)d_in[24];
    const float* f2w  = (const float*)d_in[25];
    const float* f2b  = (const float*)d_in[26];
    const float* n1g  = (const float*)d_in[27];
    const float* n1b  = (const float*)d_in[28];
    const float* n2g  = (const float*)d_in[29];
    const float* n2b  = (const float*)d_in[30];

    char* ws = (char*)d_ws;
    #define OFFK(kb) (ws + (size_t)(kb) * 1024)
    float* X    = (float*)OFFK(0);          // 4MB [2048][512]
    float* T1   = (float*)OFFK(4096);       // 4MB (spare)
    float* T3   = (float*)OFFK(8192);       // 4MB
    float* PART = (float*)OFFK(12288);      // 16MB [4][2048][512]
    unsigned short* Xb   = (unsigned short*)OFFK(45056);  // 2MB
    unsigned short* Xb0  = (unsigned short*)OFFK(47104);  // 2MB
    unsigned short* QKVb = (unsigned short*)OFFK(49152);  // 6MB [2048][1536] (aliases Hb)
    unsigned short* VT   = (unsigned short*)OFFK(55296);  // 2MB [32][64][512]
    unsigned short* CTXb = (unsigned short*)OFFK(57344);  // 2MB
    unsigned short* T3b  = (unsigned short*)OFFK(59392);  // 2MB
    unsigned short* FFb  = (unsigned short*)OFFK(61440);  // 8MB [2048][2048]
    unsigned short* W1   = (unsigned short*)OFFK(69632);  // 1.5MB [1536][512]
    unsigned short* W2   = (unsigned short*)OFFK(71168);  // 1.5MB [512][1536]
    float* b1c = (float*)OFFK(72704);                     // 6KB [1536]
    float* bc  = (float*)OFFK(72712);                     // 2KB [512]
    float* c5  = (float*)OFFK(72716);                     // [5]
    unsigned short* qkvT = (unsigned short*)OFFK(119808); // 9MB [6][1536][512]
    unsigned short* woT  = (unsigned short*)OFFK(129024); // 3MB
    unsigned short* f1wT = (unsigned short*)OFFK(132096); // 12MB
    unsigned short* f2wT = (unsigned short*)OFFK(144384); // 12MB
    unsigned short* relkb= (unsigned short*)OFFK(156672); // [6][1088][64]
    unsigned short* rvT  = (unsigned short*)OFFK(157488); // [6][64][1056]
    unsigned short* Hb   = QKVb;                          // stage-1 output alias

    // ---------------- prep ----------------
    castpad_k<<<dim3(1024, 1, 1), 256, 0, stream>>>(x, Xb0, 2048, 512, 1048576, 1048576, 1048576);
    softmax5_k<<<dim3(1), 64, 0, stream>>>(comb, c5);
    bias_build_k<<<dim3(8), 256, 0, stream>>>(t1b, r1b, s1b, t2b, r2b, s2b, c5, b1c, bc);
    // W1 stack [1536][512]
    trcast_k<<<dim3(16, 16, 1), 256, 0, stream>>>(t1w, W1, 512, 512, 512, 0, 0, nullptr, 0);
    trcast_k<<<dim3(8, 16, 1), 256, 0, stream>>>(r1w, W1 + 262144, 512, 256, 512, 0, 0, nullptr, 0);
    trcast_k<<<dim3(8, 16, 3), 256, 0, stream>>>(s1w, W1 + 393216, 512, 256, 512, 131072, 131072, nullptr, 0);
    // W2 stack [512][1536], softmax-scaled
    trcast_k<<<dim3(16, 16, 1), 256, 0, stream>>>(t2w, W2, 512, 512, 1536, 0, 0, c5, 0);
    trcast_k<<<dim3(16, 8, 1), 256, 0, stream>>>(r2w, W2 + 512, 256, 512, 1536, 0, 0, c5 + 4, 0);
    trcast_k<<<dim3(16, 8, 3), 256, 0, stream>>>(s2w, W2 + 768, 256, 512, 1536, 131072, 256, c5 + 1, 1);
    // layer weights
    trcast_k<<<dim3(16, 16, 6), 256, 0, stream>>>(wq,  qkvT,          512, 512, 512, 262144, 786432, nullptr, 0);
    trcast_k<<<dim3(16, 16, 6), 256, 0, stream>>>(wk,  qkvT + 262144, 512, 512, 512, 262144, 786432, nullptr, 0);
    trcast_k<<<dim3(16, 16, 6), 256, 0, stream>>>(wvv, qkvT + 524288, 512, 512, 512, 262144, 786432, nullptr, 0);
    trcast_k<<<dim3(16, 16, 6), 256, 0, stream>>>(wow, woT, 512, 512, 512, 262144, 262144, nullptr, 0);
    trcast_k<<<dim3(64, 16, 6), 256, 0, stream>>>(f1w, f1wT, 512, 2048, 512, 1048576, 1048576, nullptr, 0);
    trcast_k<<<dim3(16, 64, 6), 256, 0, stream>>>(f2w, f2wT, 2048, 512, 2048, 1048576, 1048576, nullptr, 0);
    trcast_k<<<dim3(2, 33, 6), 256, 0, stream>>>(relv, rvT, 1025, 64, 1056, 65600, 67584, nullptr, 0);
    castpad_k<<<dim3(272, 1, 6), 256, 0, stream>>>(relk, relkb, 1025, 64, 65600, 69632, 69632);

    // ---------------- seasonal decomposition (2 GEMMs) ----------------
    G3(64,64,true,true,true,false,false,  Xb0, W1, Hb, nullptr, b1c, 2048,1536,16,1, 512,512,1536, 1.f,
       1,0,0, 1,0,0, 1,0,0, 0,0, 1);
    G3(64,64,false,true,false,false,true, Hb, W2, X, Xb, bc, 2048,512,48,1, 1536,1536,512, 1.f,
       1,0,0, 1,0,0, 1,0,0, 0,0, 1);

    // ---------------- transformer layers ----------------
    for (int l = 0; l < NL; ++l) {
        const unsigned short* qkvTl = qkvT + (long)l * 786432;
        const unsigned short* woTl  = woT + (long)l * 262144;
        const unsigned short* f1Tl  = f1wT + (long)l * 1048576;
        const unsigned short* f2Tl  = f2wT + (long)l * 1048576;
        const unsigned short* rkl   = relkb + (long)l * 69632;
        const unsigned short* rvl   = rvT + (long)l * 67584;

        // QKV (merged)
        G3(64,64,true,false,false,false,false, Xb, qkvTl, QKVb, nullptr, nullptr, 2048,1536,16,1, 512,512,1536, 1.f,
           1,0,0, 1,0,0, 1,0,0, 0,0, 1);
        transp_v<<<dim3(16, 16, 4), 256, 0, stream>>>(QKVb + 1024, VT, 1536);
        // fused flash attention (rel-k bias in-kernel, double-buffered)
        fused_attn2<<<dim3(8, 32), 256, 0, stream>>>(QKVb, VT, rkl, rvl, CTXb);
        // out = ctx @ wo (split-K 2 partials)
        G3(64,64,false,false,false,true,false, CTXb, woTl, PART, nullptr, nullptr, 2048,512,8,2, 512,512,512, 1.f,
           1,0,0, 1,0,0, 1,0,0, 0,1048576, 2);
        // y1 = LN(x + LN(wo_out + wob + x))
        ln2x_k<<<dim3(512), 256, 0, stream>>>(PART, PART + 1048576, wob + l * 512, X,
                                              lag + l * 512, labi + l * 512,
                                              n1g + l * 512, n1b + l * 512, T3, T3b);
        // FF
        G3(64,64,true,true,true,false,false, T3b, f1Tl, FFb, nullptr, f1b + l * 2048, 2048,2048,16,1, 512,512,2048, 1.f,
           1,0,0, 1,0,0, 1,0,0, 0,0, 1);
        G3(64,64,false,false,false,true,false, FFb, f2Tl, PART, nullptr, nullptr, 2048,512,16,4, 2048,2048,512, 1.f,
           1,0,0, 1,0,0, 1,0,0, 0,1048576, 4);
        // y = LN(y1 + ff)  (sums 4 partials + bias inline)
        float* outp = (l == NL - 1) ? (float*)d_out : X;
        lnff_k<<<dim3(512), 256, 0, stream>>>(T3, PART, f2b + l * 512,
                                              n2g + l * 512, n2b + l * 512, outp, Xb);
    }
    (void)T1;
}